// Round 6
// baseline (492.528 us; speedup 1.0000x reference)
//
#include <hip/hip_runtime.h>

constexpr int N_DST1 = 50000;
constexpr int N_DST2 = 10000;
constexpr int E1     = 2000000;
constexpr int E2     = 400000;
constexpr int IN_F   = 128;
constexpr int H_F    = 256;
constexpr int N_CLS  = 47;

// Workspace layout (bytes)
constexpr size_t RP1_OFF = 0;          // 50001 int
constexpr size_t RP2_OFF = 204800;     // 10001 int
constexpr size_t BPS_OFF = 245760;     // Ws1 packed bf16 frags: 64 KB
constexpr size_t BPN_OFF = 311296;     // Wn1 packed: 64 KB
constexpr size_t BP2_OFF = 376832;     // [Ws2;Wn2] packed: 48 KB
constexpr size_t X8_OFF  = 430080;     // x fp8: 200000*128 = 25.6 MB
constexpr size_t HB_OFF  = 26030080;   // hb bf16, rows 0..N_DST2 only: 5.12 MB
constexpr size_t H8_OFF  = 31150080;   // h fp8: 50000*256 = 12.8 MB
// total ~44 MB

using f32x4  = __attribute__((ext_vector_type(4))) float;
using f32x2  = __attribute__((ext_vector_type(2))) float;
using short8 = __attribute__((ext_vector_type(8))) short;

__device__ __forceinline__ ushort f2bf(float f) {
    union { float f; unsigned u; } v; v.f = f;
    unsigned u = v.u;
    return (ushort)((u + 0x7fffu + ((u >> 16) & 1u)) >> 16);
}

// ---- fused setup: cast x->fp8 | pack weights | rowptrs ----
constexpr int CAST_BLKS = 200000 * IN_F / 8 / 256;  // 12500
constexpr int PACK_BLKS = 44;
constexpr int RP_BLKS   = (N_DST1 + N_DST2 + 2 + 255) / 256;  // 236

__global__ __launch_bounds__(256) void setup_all(
    const float* __restrict__ x, unsigned char* __restrict__ x8,
    const float* __restrict__ Ws1, const float* __restrict__ Wn1,
    const float* __restrict__ Ws2, const float* __restrict__ Wn2,
    ushort* __restrict__ bps, ushort* __restrict__ bpn, ushort* __restrict__ bp2,
    const int* __restrict__ dst1, const int* __restrict__ dst2,
    int* __restrict__ rp1, int* __restrict__ rp2) {
    int b = blockIdx.x;
    if (b < CAST_BLKS) {
        int i = b * 256 + threadIdx.x;  // groups of 8 floats
        float4 v0 = ((const float4*)x)[2 * i];
        float4 v1 = ((const float4*)x)[2 * i + 1];
        int p0 = __builtin_amdgcn_cvt_pk_fp8_f32(v0.x, v0.y, 0, false);
        p0     = __builtin_amdgcn_cvt_pk_fp8_f32(v0.z, v0.w, p0, true);
        int p1 = __builtin_amdgcn_cvt_pk_fp8_f32(v1.x, v1.y, 0, false);
        p1     = __builtin_amdgcn_cvt_pk_fp8_f32(v1.z, v1.w, p1, true);
        uint2 o; o.x = (unsigned)p0; o.y = (unsigned)p1;
        ((uint2*)x8)[i] = o;
    } else if (b < CAST_BLKS + PACK_BLKS) {
        int pb = b - CAST_BLKS;
        if (pb < 32) {
            const float* W = (pb < 16) ? Ws1 : Wn1;
            ushort* P      = (pb < 16) ? bps : bpn;
            int idx = (pb & 15) * 256 + threadIdx.x;  // 0..4095
            int lane = idx & 63, kb = (idx >> 6) & 3, nb = idx >> 8;
            int n  = nb * 16 + (lane & 15);
            int k0 = kb * 32 + ((lane >> 4) * 8);
            ushort tmp[8];
#pragma unroll
            for (int j = 0; j < 8; ++j) tmp[j] = f2bf(W[(k0 + j) * H_F + n]);
            ((uint4*)P)[idx] = *(uint4*)tmp;
        } else {
            int idx = (pb - 32) * 256 + threadIdx.x;  // 0..3071
            if (idx < 3072) {
                int lane = idx & 63, rem = idx >> 6;
                int nb = rem % 3, kb = rem / 3;
                int col = nb * 16 + (lane & 15);
                int k0  = (kb & 7) * 32 + ((lane >> 4) * 8);
                const float* W = (kb < 8) ? Ws2 : Wn2;
                ushort tmp[8];
#pragma unroll
                for (int j = 0; j < 8; ++j)
                    tmp[j] = (col < N_CLS) ? f2bf(W[(k0 + j) * N_CLS + col]) : (ushort)0;
                ((uint4*)bp2)[(kb * 3 + nb) * 64 + lane] = *(uint4*)tmp;
            }
        }
    } else {
        int idx = (b - CAST_BLKS - PACK_BLKS) * 256 + threadIdx.x;
        const int* dst; int* rp; int E; int target;
        if (idx <= N_DST1) { dst = dst1; rp = rp1; E = E1; target = idx; }
        else if (idx <= N_DST1 + 1 + N_DST2) {
            dst = dst2; rp = rp2; E = E2; target = idx - (N_DST1 + 1);
        } else return;
        int lo = 0, hi = E;
        while (lo < hi) {
            int mid = (lo + hi) >> 1;
            if (dst[mid] < target) lo = mid + 1; else hi = mid;
        }
        rp[target] = lo;
    }
}

// ---- fused layer 1: per-wave agg of 16 dsts (fp8 gathers) -> LDS A-tile ->
//      MFMA vs packed weights; writes h8 (all rows) + hb (rows < N_DST2) ----
__global__ __launch_bounds__(256) void layer1(
    const float* __restrict__ x, const unsigned char* __restrict__ x8,
    const int* __restrict__ src, const int* __restrict__ rp,
    const ushort* __restrict__ BpS, const ushort* __restrict__ BpN,
    const float* __restrict__ b1,
    ushort* __restrict__ hb, unsigned char* __restrict__ h8) {
    __shared__ ushort At[4][16 * 136];   // per-wave A-tile, stride 136 (pad)
    __shared__ ushort bsm[16 * 64 * 8];  // 16 KB B stage
    int tid = threadIdx.x, wave = tid >> 6, lane = tid & 63;
    int m0 = blockIdx.x * 64 + wave * 16;
    bool active = (m0 < N_DST1);  // 50000 % 16 == 0: active waves fully valid
    int half = lane >> 5, li = lane & 31;
    ushort* Atile = At[wave];
    const unsigned* x1 = (const unsigned*)x8;  // row stride 32 uints (128 B)

    if (active) {
        for (int m = 0; m < 16; ++m) {
            int d = m0 + m;
            int s = rp[d], e = rp[d + 1];
            int deg = e - s;
            float a0 = 0.f, a1 = 0.f, a2 = 0.f, a3 = 0.f;
            int npairs = deg >> 1;
            int j = 0;
            for (; j + 4 <= npairs; j += 4) {
                int b0 = s + 2 * j;
                int i0 = src[b0],     i1 = src[b0 + 1], i2 = src[b0 + 2], i3 = src[b0 + 3];
                int i4 = src[b0 + 4], i5 = src[b0 + 5], i6 = src[b0 + 6], i7 = src[b0 + 7];
                unsigned v0 = x1[(half ? i1 : i0) * 32 + li];
                unsigned v1 = x1[(half ? i3 : i2) * 32 + li];
                unsigned v2 = x1[(half ? i5 : i4) * 32 + li];
                unsigned v3 = x1[(half ? i7 : i6) * 32 + li];
#pragma unroll
                for (int q = 0; q < 4; ++q) {
                    unsigned v = (q == 0) ? v0 : (q == 1) ? v1 : (q == 2) ? v2 : v3;
                    f32x2 f0 = __builtin_amdgcn_cvt_pk_f32_fp8((int)v, false);
                    f32x2 f1 = __builtin_amdgcn_cvt_pk_f32_fp8((int)v, true);
                    a0 += f0[0]; a1 += f0[1]; a2 += f1[0]; a3 += f1[1];
                }
            }
            for (; j < npairs; ++j) {
                int b0 = s + 2 * j;
                int i0 = src[b0], i1 = src[b0 + 1];
                unsigned v = x1[(half ? i1 : i0) * 32 + li];
                f32x2 f0 = __builtin_amdgcn_cvt_pk_f32_fp8((int)v, false);
                f32x2 f1 = __builtin_amdgcn_cvt_pk_f32_fp8((int)v, true);
                a0 += f0[0]; a1 += f0[1]; a2 += f1[0]; a3 += f1[1];
            }
            if ((deg & 1) && half == 0) {
                unsigned v = x1[src[e - 1] * 32 + li];
                f32x2 f0 = __builtin_amdgcn_cvt_pk_f32_fp8((int)v, false);
                f32x2 f1 = __builtin_amdgcn_cvt_pk_f32_fp8((int)v, true);
                a0 += f0[0]; a1 += f0[1]; a2 += f1[0]; a3 += f1[1];
            }
            float c0 = a0 + __shfl(a0, li + 32);
            float c1 = a1 + __shfl(a1, li + 32);
            float c2 = a2 + __shfl(a2, li + 32);
            float c3 = a3 + __shfl(a3, li + 32);
            if (lane < 32) {
                float inv = 1.f / fmaxf((float)deg, 1.f);
                uint2 o;
                o.x = (unsigned)f2bf(c0 * inv) | ((unsigned)f2bf(c1 * inv) << 16);
                o.y = (unsigned)f2bf(c2 * inv) | ((unsigned)f2bf(c3 * inv) << 16);
                *(uint2*)&Atile[m * 136 + li * 4] = o;
            }
        }
    }

    f32x4 acc[16];
#pragma unroll
    for (int nb = 0; nb < 16; ++nb) acc[nb] = (f32x4){0.f, 0.f, 0.f, 0.f};
    int mloc = lane & 15;
    int koff = (lane >> 4) * 8;
    const float* Af = x + (size_t)(m0 + mloc) * IN_F;  // row < 50048 < 200000: safe

    for (int ph = 0; ph < 2; ++ph) {
        const uint4* Pg = (const uint4*)((ph == 0) ? BpS : BpN);
        for (int kb = 0; kb < 4; ++kb) {
            __syncthreads();
#pragma unroll
            for (int i = 0; i < 4; ++i) {
                int u = tid + 256 * i;
                int nb = u >> 6, l6 = u & 63;
                ((uint4*)bsm)[u] = Pg[(nb * 4 + kb) * 64 + l6];
            }
            __syncthreads();
            short8 a;
            if (ph == 0) {
                float4 q0 = *(const float4*)(Af + kb * 32 + koff);
                float4 q1 = *(const float4*)(Af + kb * 32 + koff + 4);
                a[0] = (short)f2bf(q0.x); a[1] = (short)f2bf(q0.y);
                a[2] = (short)f2bf(q0.z); a[3] = (short)f2bf(q0.w);
                a[4] = (short)f2bf(q1.x); a[5] = (short)f2bf(q1.y);
                a[6] = (short)f2bf(q1.z); a[7] = (short)f2bf(q1.w);
            } else {
                a = *(const short8*)&Atile[mloc * 136 + kb * 32 + koff];
            }
#pragma unroll
            for (int nb = 0; nb < 16; ++nb) {
                short8 b = *(const short8*)&bsm[(nb * 64 + lane) * 8];
                acc[nb] = __builtin_amdgcn_mfma_f32_16x16x32_bf16(a, b, acc[nb], 0, 0, 0);
            }
        }
    }
    if (!active) return;
    int crow0 = m0 + (lane >> 4) * 4;
    int ccol  = lane & 15;
#pragma unroll
    for (int nb = 0; nb < 16; ++nb) {
        float bias = b1[nb * 16 + ccol];
#pragma unroll
        for (int r = 0; r < 4; ++r) {
            float v = fmaxf(acc[nb][r] + bias, 0.f);
            int row = crow0 + r;
            size_t col = (size_t)nb * 16 + ccol;
            int p = __builtin_amdgcn_cvt_pk_fp8_f32(v, v, 0, false);
            h8[(size_t)row * H_F + col] = (unsigned char)(p & 0xff);
            if (row < N_DST2) hb[(size_t)row * H_F + col] = f2bf(v);
        }
    }
}

// ---- fused layer 2: per-wave agg of 16 dst2 (fp8 gathers from h8) -> LDS ->
//      MFMA K=512 [hb | agg], N padded to 48; writes out fp32 ----
__global__ __launch_bounds__(256) void layer2(
    const ushort* __restrict__ hb, const unsigned char* __restrict__ h8,
    const int* __restrict__ src, const int* __restrict__ rp,
    const ushort* __restrict__ P2, const float* __restrict__ b2,
    float* __restrict__ out) {
    __shared__ ushort At[4][16 * 264];  // per-wave A-tile, stride 264 (pad)
    int tid = threadIdx.x, wave = tid >> 6, lane = tid & 63;
    int m0 = blockIdx.x * 64 + wave * 16;
    if (m0 >= N_DST2) return;  // no barriers in this kernel: early-out safe
    int half = lane >> 5, li = lane & 31;
    ushort* Atile = At[wave];
    const uint2* h2 = (const uint2*)h8;  // row stride 32 uint2 (256 B)

    for (int m = 0; m < 16; ++m) {
        int d = m0 + m;
        int s = rp[d], e = rp[d + 1];
        int deg = e - s;
        float a[8] = {};
        int npairs = deg >> 1;
        int j = 0;
        for (; j + 2 <= npairs; j += 2) {
            int b0 = s + 2 * j;
            int i0 = src[b0], i1 = src[b0 + 1], i2 = src[b0 + 2], i3 = src[b0 + 3];
            uint2 v0 = h2[(half ? i1 : i0) * 32 + li];
            uint2 v1 = h2[(half ? i3 : i2) * 32 + li];
#pragma unroll
            for (int q = 0; q < 2; ++q) {
                uint2 v = q ? v1 : v0;
                f32x2 f0 = __builtin_amdgcn_cvt_pk_f32_fp8((int)v.x, false);
                f32x2 f1 = __builtin_amdgcn_cvt_pk_f32_fp8((int)v.x, true);
                f32x2 f2 = __builtin_amdgcn_cvt_pk_f32_fp8((int)v.y, false);
                f32x2 f3 = __builtin_amdgcn_cvt_pk_f32_fp8((int)v.y, true);
                a[0] += f0[0]; a[1] += f0[1]; a[2] += f1[0]; a[3] += f1[1];
                a[4] += f2[0]; a[5] += f2[1]; a[6] += f3[0]; a[7] += f3[1];
            }
        }
        for (; j < npairs; ++j) {
            int b0 = s + 2 * j;
            int i0 = src[b0], i1 = src[b0 + 1];
            uint2 v = h2[(half ? i1 : i0) * 32 + li];
            f32x2 f0 = __builtin_amdgcn_cvt_pk_f32_fp8((int)v.x, false);
            f32x2 f1 = __builtin_amdgcn_cvt_pk_f32_fp8((int)v.x, true);
            f32x2 f2 = __builtin_amdgcn_cvt_pk_f32_fp8((int)v.y, false);
            f32x2 f3 = __builtin_amdgcn_cvt_pk_f32_fp8((int)v.y, true);
            a[0] += f0[0]; a[1] += f0[1]; a[2] += f1[0]; a[3] += f1[1];
            a[4] += f2[0]; a[5] += f2[1]; a[6] += f3[0]; a[7] += f3[1];
        }
        if ((deg & 1) && half == 0) {
            uint2 v = h2[src[e - 1] * 32 + li];
            f32x2 f0 = __builtin_amdgcn_cvt_pk_f32_fp8((int)v.x, false);
            f32x2 f1 = __builtin_amdgcn_cvt_pk_f32_fp8((int)v.x, true);
            f32x2 f2 = __builtin_amdgcn_cvt_pk_f32_fp8((int)v.y, false);
            f32x2 f3 = __builtin_amdgcn_cvt_pk_f32_fp8((int)v.y, true);
            a[0] += f0[0]; a[1] += f0[1]; a[2] += f1[0]; a[3] += f1[1];
            a[4] += f2[0]; a[5] += f2[1]; a[6] += f3[0]; a[7] += f3[1];
        }
        float c[8];
#pragma unroll
        for (int q = 0; q < 8; ++q) c[q] = a[q] + __shfl(a[q], li + 32);
        if (lane < 32) {
            float inv = 1.f / fmaxf((float)deg, 1.f);
            uint4 o;
            o.x = (unsigned)f2bf(c[0] * inv) | ((unsigned)f2bf(c[1] * inv) << 16);
            o.y = (unsigned)f2bf(c[2] * inv) | ((unsigned)f2bf(c[3] * inv) << 16);
            o.z = (unsigned)f2bf(c[4] * inv) | ((unsigned)f2bf(c[5] * inv) << 16);
            o.w = (unsigned)f2bf(c[6] * inv) | ((unsigned)f2bf(c[7] * inv) << 16);
            *(uint4*)&Atile[m * 264 + li * 8] = o;
        }
    }

    f32x4 acc[3];
#pragma unroll
    for (int nb = 0; nb < 3; ++nb) acc[nb] = (f32x4){0.f, 0.f, 0.f, 0.f};
    int mloc = lane & 15;
    int koff = (lane >> 4) * 8;
    const ushort* Ah = hb + (size_t)(m0 + mloc) * H_F;
#pragma unroll
    for (int kb = 0; kb < 16; ++kb) {
        short8 a;
        if (kb < 8) a = *(const short8*)(Ah + kb * 32 + koff);
        else        a = *(const short8*)&Atile[mloc * 264 + (kb - 8) * 32 + koff];
#pragma unroll
        for (int nb = 0; nb < 3; ++nb) {
            short8 b = *(const short8*)(P2 + ((size_t)(kb * 3 + nb) * 64 + lane) * 8);
            acc[nb] = __builtin_amdgcn_mfma_f32_16x16x32_bf16(a, b, acc[nb], 0, 0, 0);
        }
    }
    int crow0 = m0 + (lane >> 4) * 4;
    int ccol  = lane & 15;
#pragma unroll
    for (int nb = 0; nb < 3; ++nb) {
        int col = nb * 16 + ccol;
        if (col < N_CLS) {
            float bias = b2[col];
#pragma unroll
            for (int r = 0; r < 4; ++r)
                out[(size_t)(crow0 + r) * N_CLS + col] = acc[nb][r] + bias;
        }
    }
}

extern "C" void kernel_launch(void* const* d_in, const int* in_sizes, int n_in,
                              void* d_out, int out_size, void* d_ws, size_t ws_size,
                              hipStream_t stream) {
    const float* x   = (const float*)d_in[0];
    const float* Ws1 = (const float*)d_in[1];
    const float* Wn1 = (const float*)d_in[2];
    const float* b1  = (const float*)d_in[3];
    const float* Ws2 = (const float*)d_in[4];
    const float* Wn2 = (const float*)d_in[5];
    const float* b2  = (const float*)d_in[6];
    const int* src1  = (const int*)d_in[7];
    const int* dst1  = (const int*)d_in[8];
    const int* src2  = (const int*)d_in[9];
    const int* dst2  = (const int*)d_in[10];
    float* out = (float*)d_out;

    char* ws = (char*)d_ws;
    int*           rp1 = (int*)(ws + RP1_OFF);
    int*           rp2 = (int*)(ws + RP2_OFF);
    ushort*        bps = (ushort*)(ws + BPS_OFF);
    ushort*        bpn = (ushort*)(ws + BPN_OFF);
    ushort*        bp2 = (ushort*)(ws + BP2_OFF);
    unsigned char* x8  = (unsigned char*)(ws + X8_OFF);
    ushort*        hb  = (ushort*)(ws + HB_OFF);
    unsigned char* h8  = (unsigned char*)(ws + H8_OFF);

    setup_all<<<CAST_BLKS + PACK_BLKS + RP_BLKS, 256, 0, stream>>>(
        x, x8, Ws1, Wn1, Ws2, Wn2, bps, bpn, bp2, dst1, dst2, rp1, rp2);
    layer1<<<(N_DST1 + 63) / 64, 256, 0, stream>>>(
        x, x8, src1, rp1, bps, bpn, b1, hb, h8);
    layer2<<<(N_DST2 + 63) / 64, 256, 0, stream>>>(
        hb, h8, src2, rp2, bp2, b2, out);
}

// Round 7
// 319.321 us; speedup vs baseline: 1.5424x; 1.5424x over previous
//
#include <hip/hip_runtime.h>

constexpr int N_DST1 = 50000;
constexpr int N_DST2 = 10000;
constexpr int E1     = 2000000;
constexpr int E2     = 400000;
constexpr int IN_F   = 128;
constexpr int H_F    = 256;
constexpr int N_CLS  = 47;

// Workspace layout (bytes)
constexpr size_t RP1_OFF = 0;          // 50001 int
constexpr size_t RP2_OFF = 204800;     // 10001 int
constexpr size_t BPS_OFF = 245760;     // Ws1 packed bf16 frags: 64 KB
constexpr size_t BPN_OFF = 311296;     // Wn1 packed: 64 KB
constexpr size_t BP2_OFF = 376832;     // [Ws2;Wn2] packed: 48 KB
constexpr size_t X8_OFF  = 430080;     // x fp8: 200000*128 = 25.6 MB
constexpr size_t HN1_OFF = 26030080;   // hn1 bf16: 12.8 MB
constexpr size_t HB_OFF  = 38830080;   // h bf16: 25.6 MB
constexpr size_t H8_OFF  = 64430080;   // h fp8: 12.8 MB
constexpr size_t HN2_OFF = 77230080;   // hn2 bf16: 5.12 MB
// total ~82.4 MB

using f32x4  = __attribute__((ext_vector_type(4))) float;
using f32x2  = __attribute__((ext_vector_type(2))) float;
using short8 = __attribute__((ext_vector_type(8))) short;

__device__ __forceinline__ ushort f2bf(float f) {
    union { float f; unsigned u; } v; v.f = f;
    unsigned u = v.u;
    return (ushort)((u + 0x7fffu + ((u >> 16) & 1u)) >> 16);
}

// ---- fused setup: cast x->fp8 | pack weights | rowptrs ----
constexpr int CAST_BLKS = 200000 * IN_F / 8 / 256;  // 12500
constexpr int PACK_BLKS = 44;
constexpr int RP_BLKS   = (N_DST1 + N_DST2 + 2 + 255) / 256;  // 236

__global__ __launch_bounds__(256) void setup_all(
    const float* __restrict__ x, unsigned char* __restrict__ x8,
    const float* __restrict__ Ws1, const float* __restrict__ Wn1,
    const float* __restrict__ Ws2, const float* __restrict__ Wn2,
    ushort* __restrict__ bps, ushort* __restrict__ bpn, ushort* __restrict__ bp2,
    const int* __restrict__ dst1, const int* __restrict__ dst2,
    int* __restrict__ rp1, int* __restrict__ rp2) {
    int b = blockIdx.x;
    if (b < CAST_BLKS) {
        int i = b * 256 + threadIdx.x;  // groups of 8 floats
        float4 v0 = ((const float4*)x)[2 * i];
        float4 v1 = ((const float4*)x)[2 * i + 1];
        int p0 = __builtin_amdgcn_cvt_pk_fp8_f32(v0.x, v0.y, 0, false);
        p0     = __builtin_amdgcn_cvt_pk_fp8_f32(v0.z, v0.w, p0, true);
        int p1 = __builtin_amdgcn_cvt_pk_fp8_f32(v1.x, v1.y, 0, false);
        p1     = __builtin_amdgcn_cvt_pk_fp8_f32(v1.z, v1.w, p1, true);
        uint2 o; o.x = (unsigned)p0; o.y = (unsigned)p1;
        ((uint2*)x8)[i] = o;
    } else if (b < CAST_BLKS + PACK_BLKS) {
        int pb = b - CAST_BLKS;
        if (pb < 32) {
            const float* W = (pb < 16) ? Ws1 : Wn1;
            ushort* P      = (pb < 16) ? bps : bpn;
            int idx = (pb & 15) * 256 + threadIdx.x;  // 0..4095
            int lane = idx & 63, kb = (idx >> 6) & 3, nb = idx >> 8;
            int n  = nb * 16 + (lane & 15);
            int k0 = kb * 32 + ((lane >> 4) * 8);
            ushort tmp[8];
#pragma unroll
            for (int j = 0; j < 8; ++j) tmp[j] = f2bf(W[(k0 + j) * H_F + n]);
            ((uint4*)P)[idx] = *(uint4*)tmp;
        } else {
            int idx = (pb - 32) * 256 + threadIdx.x;  // 0..3071
            if (idx < 3072) {
                int lane = idx & 63, rem = idx >> 6;
                int nb = rem % 3, kb = rem / 3;
                int col = nb * 16 + (lane & 15);
                int k0  = (kb & 7) * 32 + ((lane >> 4) * 8);
                const float* W = (kb < 8) ? Ws2 : Wn2;
                ushort tmp[8];
#pragma unroll
                for (int j = 0; j < 8; ++j)
                    tmp[j] = (col < N_CLS) ? f2bf(W[(k0 + j) * N_CLS + col]) : (ushort)0;
                ((uint4*)bp2)[(kb * 3 + nb) * 64 + lane] = *(uint4*)tmp;
            }
        }
    } else {
        int idx = (b - CAST_BLKS - PACK_BLKS) * 256 + threadIdx.x;
        const int* dst; int* rp; int E; int target;
        if (idx <= N_DST1) { dst = dst1; rp = rp1; E = E1; target = idx; }
        else if (idx <= N_DST1 + 1 + N_DST2) {
            dst = dst2; rp = rp2; E = E2; target = idx - (N_DST1 + 1);
        } else return;
        int lo = 0, hi = E;
        while (lo < hi) {
            int mid = (lo + hi) >> 1;
            if (dst[mid] < target) lo = mid + 1; else hi = mid;
        }
        rp[target] = lo;
    }
}

// ---- layer-1 mean agg: 4 waves/block, one dst per wave; 2 edges per load ----
// x8 row = 128 B = 32 uints; lane t in half h=(t>>5) covers feats 4*(t&31)..+3
__global__ __launch_bounds__(256) void agg1b(const unsigned char* __restrict__ x8,
                                             const int* __restrict__ src,
                                             const int* __restrict__ rp,
                                             ushort* __restrict__ hn) {
    int t = threadIdx.x & 63;
    int d = blockIdx.x * 4 + (threadIdx.x >> 6);
    int s = rp[d], e = rp[d + 1];
    const unsigned* x1 = (const unsigned*)x8;  // row stride 32 uints
    int half = t >> 5, li = t & 31;
    float a0 = 0.f, a1 = 0.f, a2 = 0.f, a3 = 0.f;
    int deg = e - s;
    int npairs = deg >> 1;
    int j = 0;
    for (; j + 8 <= npairs; j += 8) {
        int b0 = s + 2 * j;
        unsigned v[8];
#pragma unroll
        for (int q = 0; q < 8; ++q) {
            int ia = src[b0 + 2 * q], ib = src[b0 + 2 * q + 1];
            v[q] = x1[(half ? ib : ia) * 32 + li];
        }
#pragma unroll
        for (int q = 0; q < 8; ++q) {
            f32x2 f0 = __builtin_amdgcn_cvt_pk_f32_fp8((int)v[q], false);
            f32x2 f1 = __builtin_amdgcn_cvt_pk_f32_fp8((int)v[q], true);
            a0 += f0[0]; a1 += f0[1]; a2 += f1[0]; a3 += f1[1];
        }
    }
    for (; j < npairs; ++j) {
        int b0 = s + 2 * j;
        int i0 = src[b0], i1 = src[b0 + 1];
        unsigned v = x1[(half ? i1 : i0) * 32 + li];
        f32x2 f0 = __builtin_amdgcn_cvt_pk_f32_fp8((int)v, false);
        f32x2 f1 = __builtin_amdgcn_cvt_pk_f32_fp8((int)v, true);
        a0 += f0[0]; a1 += f0[1]; a2 += f1[0]; a3 += f1[1];
    }
    if ((deg & 1) && half == 0) {
        unsigned v = x1[src[e - 1] * 32 + li];
        f32x2 f0 = __builtin_amdgcn_cvt_pk_f32_fp8((int)v, false);
        f32x2 f1 = __builtin_amdgcn_cvt_pk_f32_fp8((int)v, true);
        a0 += f0[0]; a1 += f0[1]; a2 += f1[0]; a3 += f1[1];
    }
    // combine parity halves (valid for lanes 0..31 of each wave)
    float c0 = a0 + __shfl(a0, li + 32);
    float c1 = a1 + __shfl(a1, li + 32);
    float c2 = a2 + __shfl(a2, li + 32);
    float c3 = a3 + __shfl(a3, li + 32);
    if (t < 32) {
        float inv = 1.f / fmaxf((float)deg, 1.f);
        uint2 o;
        o.x = (unsigned)f2bf(c0 * inv) | ((unsigned)f2bf(c1 * inv) << 16);
        o.y = (unsigned)f2bf(c2 * inv) | ((unsigned)f2bf(c3 * inv) << 16);
        ((uint2*)hn)[d * 32 + li] = o;
    }
}

// ---- layer-2 mean agg: 4 waves/block, one dst per wave; 2 edges per uint2 ----
__global__ __launch_bounds__(256) void agg2b(const unsigned char* __restrict__ h8,
                                             const int* __restrict__ src,
                                             const int* __restrict__ rp,
                                             ushort* __restrict__ hn) {
    int t = threadIdx.x & 63;
    int d = blockIdx.x * 4 + (threadIdx.x >> 6);
    int s = rp[d], e = rp[d + 1];
    const uint2* h2 = (const uint2*)h8;  // row stride 32 uint2
    int half = t >> 5, li = t & 31;
    float a[8] = {};
    int deg = e - s;
    int npairs = deg >> 1;
    int j = 0;
    for (; j + 4 <= npairs; j += 4) {
        int b0 = s + 2 * j;
        uint2 v[4];
#pragma unroll
        for (int q = 0; q < 4; ++q) {
            int ia = src[b0 + 2 * q], ib = src[b0 + 2 * q + 1];
            v[q] = h2[(half ? ib : ia) * 32 + li];
        }
#pragma unroll
        for (int q = 0; q < 4; ++q) {
            f32x2 f0 = __builtin_amdgcn_cvt_pk_f32_fp8((int)v[q].x, false);
            f32x2 f1 = __builtin_amdgcn_cvt_pk_f32_fp8((int)v[q].x, true);
            f32x2 f2 = __builtin_amdgcn_cvt_pk_f32_fp8((int)v[q].y, false);
            f32x2 f3 = __builtin_amdgcn_cvt_pk_f32_fp8((int)v[q].y, true);
            a[0] += f0[0]; a[1] += f0[1]; a[2] += f1[0]; a[3] += f1[1];
            a[4] += f2[0]; a[5] += f2[1]; a[6] += f3[0]; a[7] += f3[1];
        }
    }
    for (; j < npairs; ++j) {
        int b0 = s + 2 * j;
        int i0 = src[b0], i1 = src[b0 + 1];
        uint2 v = h2[(half ? i1 : i0) * 32 + li];
        f32x2 f0 = __builtin_amdgcn_cvt_pk_f32_fp8((int)v.x, false);
        f32x2 f1 = __builtin_amdgcn_cvt_pk_f32_fp8((int)v.x, true);
        f32x2 f2 = __builtin_amdgcn_cvt_pk_f32_fp8((int)v.y, false);
        f32x2 f3 = __builtin_amdgcn_cvt_pk_f32_fp8((int)v.y, true);
        a[0] += f0[0]; a[1] += f0[1]; a[2] += f1[0]; a[3] += f1[1];
        a[4] += f2[0]; a[5] += f2[1]; a[6] += f3[0]; a[7] += f3[1];
    }
    if ((deg & 1) && half == 0) {
        uint2 v = h2[src[e - 1] * 32 + li];
        f32x2 f0 = __builtin_amdgcn_cvt_pk_f32_fp8((int)v.x, false);
        f32x2 f1 = __builtin_amdgcn_cvt_pk_f32_fp8((int)v.x, true);
        f32x2 f2 = __builtin_amdgcn_cvt_pk_f32_fp8((int)v.y, false);
        f32x2 f3 = __builtin_amdgcn_cvt_pk_f32_fp8((int)v.y, true);
        a[0] += f0[0]; a[1] += f0[1]; a[2] += f1[0]; a[3] += f1[1];
        a[4] += f2[0]; a[5] += f2[1]; a[6] += f3[0]; a[7] += f3[1];
    }
    float c[8];
#pragma unroll
    for (int q = 0; q < 8; ++q) c[q] = a[q] + __shfl(a[q], li + 32);
    if (t < 32) {
        float inv = 1.f / fmaxf((float)deg, 1.f);
        uint4 o;
        o.x = (unsigned)f2bf(c[0] * inv) | ((unsigned)f2bf(c[1] * inv) << 16);
        o.y = (unsigned)f2bf(c[2] * inv) | ((unsigned)f2bf(c[3] * inv) << 16);
        o.z = (unsigned)f2bf(c[4] * inv) | ((unsigned)f2bf(c[5] * inv) << 16);
        o.w = (unsigned)f2bf(c[6] * inv) | ((unsigned)f2bf(c[7] * inv) << 16);
        ((uint4*)hn)[d * 32 + li] = o;
    }
}

// ---- layer 1 GEMM (MFMA; self-A from fp32 x, neigh-A from bf16 hn1) ----
__global__ __launch_bounds__(256) void gemm1_mfma(
    const float* __restrict__ x, const ushort* __restrict__ hn1,
    const ushort* __restrict__ BpS, const ushort* __restrict__ BpN,
    const float* __restrict__ b1, ushort* __restrict__ hb,
    unsigned char* __restrict__ h8) {
    __shared__ ushort bsm[16 * 64 * 8];  // 16 KB stage
    int tid = threadIdx.x;
    int wave = tid >> 6, lane = tid & 63;
    int m0 = (blockIdx.x * 4 + wave) * 16;
    int mrow = m0 + (lane & 15);
    bool active = (m0 < N_DST1);
    if (mrow >= N_DST1) mrow = 0;
    int koff = (lane >> 4) * 8;

    f32x4 acc[16];
#pragma unroll
    for (int nb = 0; nb < 16; ++nb) acc[nb] = (f32x4){0.f, 0.f, 0.f, 0.f};

    for (int ph = 0; ph < 2; ++ph) {
        const uint4* Pg = (const uint4*)((ph == 0) ? BpS : BpN);
        const float*  Af = x   + (size_t)mrow * IN_F;
        const ushort* Ah = hn1 + (size_t)mrow * IN_F;
        for (int kb = 0; kb < 4; ++kb) {
            __syncthreads();
#pragma unroll
            for (int i = 0; i < 4; ++i) {
                int u = tid + 256 * i;
                int nb = u >> 6, l6 = u & 63;
                ((uint4*)bsm)[u] = Pg[(nb * 4 + kb) * 64 + l6];
            }
            __syncthreads();
            short8 a;
            if (ph == 0) {
                float4 a0 = *(const float4*)(Af + kb * 32 + koff);
                float4 a1 = *(const float4*)(Af + kb * 32 + koff + 4);
                a[0] = (short)f2bf(a0.x); a[1] = (short)f2bf(a0.y);
                a[2] = (short)f2bf(a0.z); a[3] = (short)f2bf(a0.w);
                a[4] = (short)f2bf(a1.x); a[5] = (short)f2bf(a1.y);
                a[6] = (short)f2bf(a1.z); a[7] = (short)f2bf(a1.w);
            } else {
                a = *(const short8*)(Ah + kb * 32 + koff);
            }
#pragma unroll
            for (int nb = 0; nb < 16; ++nb) {
                short8 b = *(const short8*)&bsm[(nb * 64 + lane) * 8];
                acc[nb] = __builtin_amdgcn_mfma_f32_16x16x32_bf16(a, b, acc[nb], 0, 0, 0);
            }
        }
    }
    if (!active) return;
    int crow0 = m0 + (lane >> 4) * 4;
    int ccol  = lane & 15;
#pragma unroll
    for (int nb = 0; nb < 16; ++nb) {
        float bias = b1[nb * 16 + ccol];
#pragma unroll
        for (int r = 0; r < 4; ++r) {
            int row = crow0 + r;
            if (row < N_DST1) {
                float v = fmaxf(acc[nb][r] + bias, 0.f);
                size_t col = (size_t)nb * 16 + ccol;
                hb[(size_t)row * H_F + col] = f2bf(v);
                int p = __builtin_amdgcn_cvt_pk_fp8_f32(v, v, 0, false);
                h8[(size_t)row * H_F + col] = (unsigned char)(p & 0xff);
            }
        }
    }
}

// ---- layer 2 GEMM (MFMA, K=512 over [hb|hn2], N padded to 48) ----
__global__ __launch_bounds__(256) void gemm2_mfma(
    const ushort* __restrict__ hb, const ushort* __restrict__ hn2,
    const ushort* __restrict__ P2, const float* __restrict__ b2,
    float* __restrict__ out) {
    int tid = threadIdx.x;
    int wave = tid >> 6, lane = tid & 63;
    int m0 = (blockIdx.x * 4 + wave) * 16;
    if (m0 >= N_DST2) return;
    int mrow = m0 + (lane & 15);
    int koff = (lane >> 4) * 8;

    f32x4 acc[3];
#pragma unroll
    for (int nb = 0; nb < 3; ++nb) acc[nb] = (f32x4){0.f, 0.f, 0.f, 0.f};

#pragma unroll
    for (int kb = 0; kb < 16; ++kb) {
        const ushort* A = (kb < 8)
            ? (hb  + (size_t)mrow * H_F + kb * 32 + koff)
            : (hn2 + (size_t)mrow * H_F + (kb - 8) * 32 + koff);
        short8 a = *(const short8*)A;
#pragma unroll
        for (int nb = 0; nb < 3; ++nb) {
            short8 b = *(const short8*)(P2 + ((size_t)(kb * 3 + nb) * 64 + lane) * 8);
            acc[nb] = __builtin_amdgcn_mfma_f32_16x16x32_bf16(a, b, acc[nb], 0, 0, 0);
        }
    }
    int crow0 = m0 + (lane >> 4) * 4;
    int ccol  = lane & 15;
#pragma unroll
    for (int nb = 0; nb < 3; ++nb) {
        int col = nb * 16 + ccol;
        if (col < N_CLS) {
            float bias = b2[col];
#pragma unroll
            for (int r = 0; r < 4; ++r)
                out[(size_t)(crow0 + r) * N_CLS + col] = acc[nb][r] + bias;
        }
    }
}

extern "C" void kernel_launch(void* const* d_in, const int* in_sizes, int n_in,
                              void* d_out, int out_size, void* d_ws, size_t ws_size,
                              hipStream_t stream) {
    const float* x   = (const float*)d_in[0];
    const float* Ws1 = (const float*)d_in[1];
    const float* Wn1 = (const float*)d_in[2];
    const float* b1  = (const float*)d_in[3];
    const float* Ws2 = (const float*)d_in[4];
    const float* Wn2 = (const float*)d_in[5];
    const float* b2  = (const float*)d_in[6];
    const int* src1  = (const int*)d_in[7];
    const int* dst1  = (const int*)d_in[8];
    const int* src2  = (const int*)d_in[9];
    const int* dst2  = (const int*)d_in[10];
    float* out = (float*)d_out;

    char* ws = (char*)d_ws;
    int*           rp1 = (int*)(ws + RP1_OFF);
    int*           rp2 = (int*)(ws + RP2_OFF);
    ushort*        bps = (ushort*)(ws + BPS_OFF);
    ushort*        bpn = (ushort*)(ws + BPN_OFF);
    ushort*        bp2 = (ushort*)(ws + BP2_OFF);
    unsigned char* x8  = (unsigned char*)(ws + X8_OFF);
    ushort*        hn1 = (ushort*)(ws + HN1_OFF);
    ushort*        hb  = (ushort*)(ws + HB_OFF);
    unsigned char* h8  = (unsigned char*)(ws + H8_OFF);
    ushort*        hn2 = (ushort*)(ws + HN2_OFF);

    setup_all<<<CAST_BLKS + PACK_BLKS + RP_BLKS, 256, 0, stream>>>(
        x, x8, Ws1, Wn1, Ws2, Wn2, bps, bpn, bp2, dst1, dst2, rp1, rp2);
    agg1b<<<N_DST1 / 4, 256, 0, stream>>>(x8, src1, rp1, hn1);
    gemm1_mfma<<<(N_DST1 / 16 + 3) / 4, 256, 0, stream>>>(x, hn1, bps, bpn, b1, hb, h8);
    agg2b<<<N_DST2 / 4, 256, 0, stream>>>(h8, src2, rp2, hn2);
    gemm2_mfma<<<(N_DST2 / 16 + 3) / 4, 256, 0, stream>>>(hb, hn2, bp2, b2, out);
}

// Round 8
// 304.169 us; speedup vs baseline: 1.6193x; 1.0498x over previous
//
#include <hip/hip_runtime.h>

constexpr int N_DST1 = 50000;
constexpr int N_DST2 = 10000;
constexpr int E1     = 2000000;
constexpr int E2     = 400000;
constexpr int IN_F   = 128;
constexpr int H_F    = 256;
constexpr int N_CLS  = 47;

// Workspace layout (bytes)
constexpr size_t RP1_OFF = 0;          // 50001 int
constexpr size_t RP2_OFF = 204800;     // 10001 int
constexpr size_t BPS_OFF = 245760;     // Ws1 packed bf16 frags: 64 KB
constexpr size_t BPN_OFF = 311296;     // Wn1 packed: 64 KB
constexpr size_t BP2_OFF = 376832;     // [Ws2;Wn2] packed: 48 KB
constexpr size_t X8_OFF  = 430080;     // x fp8: 200000*128 = 25.6 MB
constexpr size_t HN1_OFF = 26030080;   // hn1 bf16: 12.8 MB
constexpr size_t HB_OFF  = 38830080;   // h bf16: 25.6 MB
constexpr size_t H8_OFF  = 64430080;   // h fp8: 12.8 MB
constexpr size_t HN2_OFF = 77230080;   // hn2 bf16: 5.12 MB
// total ~82.4 MB

using f32x4  = __attribute__((ext_vector_type(4))) float;
using f32x2  = __attribute__((ext_vector_type(2))) float;
using short8 = __attribute__((ext_vector_type(8))) short;

__device__ __forceinline__ ushort f2bf(float f) {
    union { float f; unsigned u; } v; v.f = f;
    unsigned u = v.u;
    return (ushort)((u + 0x7fffu + ((u >> 16) & 1u)) >> 16);
}

// ---- fused setup: cast x->fp8 | pack weights | rowptrs ----
constexpr int CAST_BLKS = 200000 * IN_F / 8 / 256;  // 12500
constexpr int PACK_BLKS = 44;
constexpr int RP_BLKS   = (N_DST1 + N_DST2 + 2 + 255) / 256;  // 236

__global__ __launch_bounds__(256) void setup_all(
    const float* __restrict__ x, unsigned char* __restrict__ x8,
    const float* __restrict__ Ws1, const float* __restrict__ Wn1,
    const float* __restrict__ Ws2, const float* __restrict__ Wn2,
    ushort* __restrict__ bps, ushort* __restrict__ bpn, ushort* __restrict__ bp2,
    const int* __restrict__ dst1, const int* __restrict__ dst2,
    int* __restrict__ rp1, int* __restrict__ rp2) {
    int b = blockIdx.x;
    if (b < CAST_BLKS) {
        int i = b * 256 + threadIdx.x;  // groups of 8 floats
        float4 v0 = ((const float4*)x)[2 * i];
        float4 v1 = ((const float4*)x)[2 * i + 1];
        int p0 = __builtin_amdgcn_cvt_pk_fp8_f32(v0.x, v0.y, 0, false);
        p0     = __builtin_amdgcn_cvt_pk_fp8_f32(v0.z, v0.w, p0, true);
        int p1 = __builtin_amdgcn_cvt_pk_fp8_f32(v1.x, v1.y, 0, false);
        p1     = __builtin_amdgcn_cvt_pk_fp8_f32(v1.z, v1.w, p1, true);
        uint2 o; o.x = (unsigned)p0; o.y = (unsigned)p1;
        ((uint2*)x8)[i] = o;
    } else if (b < CAST_BLKS + PACK_BLKS) {
        int pb = b - CAST_BLKS;
        if (pb < 32) {
            const float* W = (pb < 16) ? Ws1 : Wn1;
            ushort* P      = (pb < 16) ? bps : bpn;
            int idx = (pb & 15) * 256 + threadIdx.x;  // 0..4095
            int lane = idx & 63, kb = (idx >> 6) & 3, nb = idx >> 8;
            int n  = nb * 16 + (lane & 15);
            int k0 = kb * 32 + ((lane >> 4) * 8);
            ushort tmp[8];
#pragma unroll
            for (int j = 0; j < 8; ++j) tmp[j] = f2bf(W[(k0 + j) * H_F + n]);
            ((uint4*)P)[idx] = *(uint4*)tmp;
        } else {
            int idx = (pb - 32) * 256 + threadIdx.x;  // 0..3071
            if (idx < 3072) {
                int lane = idx & 63, rem = idx >> 6;
                int nb = rem % 3, kb = rem / 3;
                int col = nb * 16 + (lane & 15);
                int k0  = (kb & 7) * 32 + ((lane >> 4) * 8);
                const float* W = (kb < 8) ? Ws2 : Wn2;
                ushort tmp[8];
#pragma unroll
                for (int j = 0; j < 8; ++j)
                    tmp[j] = (col < N_CLS) ? f2bf(W[(k0 + j) * N_CLS + col]) : (ushort)0;
                ((uint4*)bp2)[(kb * 3 + nb) * 64 + lane] = *(uint4*)tmp;
            }
        }
    } else {
        int idx = (b - CAST_BLKS - PACK_BLKS) * 256 + threadIdx.x;
        const int* dst; int* rp; int E; int target;
        if (idx <= N_DST1) { dst = dst1; rp = rp1; E = E1; target = idx; }
        else if (idx <= N_DST1 + 1 + N_DST2) {
            dst = dst2; rp = rp2; E = E2; target = idx - (N_DST1 + 1);
        } else return;
        int lo = 0, hi = E;
        while (lo < hi) {
            int mid = (lo + hi) >> 1;
            if (dst[mid] < target) lo = mid + 1; else hi = mid;
        }
        rp[target] = lo;
    }
}

// ---- layer-1 mean agg: one wave/dst; 8 edges per dwordx4 wave-load ----
// x8 row = 128 B = 8 uint4. lane t: edge-slot g=t>>3, chunk c=t&7 (16 B).
__global__ __launch_bounds__(256) void agg1b(const unsigned char* __restrict__ x8,
                                             const int* __restrict__ src,
                                             const int* __restrict__ rp,
                                             ushort* __restrict__ hn) {
    int t = threadIdx.x & 63;
    int d = blockIdx.x * 4 + (threadIdx.x >> 6);
    int s = rp[d], e = rp[d + 1];
    int deg = e - s;
    const uint4* x4 = (const uint4*)x8;  // row stride 8 uint4
    int g = t >> 3, c = t & 7;
    float a[16] = {};
    auto acc16 = [&](uint4 v) {
        f32x2 f;
        f = __builtin_amdgcn_cvt_pk_f32_fp8((int)v.x, false); a[0]  += f[0]; a[1]  += f[1];
        f = __builtin_amdgcn_cvt_pk_f32_fp8((int)v.x, true);  a[2]  += f[0]; a[3]  += f[1];
        f = __builtin_amdgcn_cvt_pk_f32_fp8((int)v.y, false); a[4]  += f[0]; a[5]  += f[1];
        f = __builtin_amdgcn_cvt_pk_f32_fp8((int)v.y, true);  a[6]  += f[0]; a[7]  += f[1];
        f = __builtin_amdgcn_cvt_pk_f32_fp8((int)v.z, false); a[8]  += f[0]; a[9]  += f[1];
        f = __builtin_amdgcn_cvt_pk_f32_fp8((int)v.z, true);  a[10] += f[0]; a[11] += f[1];
        f = __builtin_amdgcn_cvt_pk_f32_fp8((int)v.w, false); a[12] += f[0]; a[13] += f[1];
        f = __builtin_amdgcn_cvt_pk_f32_fp8((int)v.w, true);  a[14] += f[0]; a[15] += f[1];
    };
    int nfull = deg >> 3;
    int j = 0;
    for (; j + 2 <= nfull; j += 2) {
        int e0 = src[s + 8 * j + g];
        int e1 = src[s + 8 * j + 8 + g];
        uint4 v0 = x4[(size_t)e0 * 8 + c];
        uint4 v1 = x4[(size_t)e1 * 8 + c];
        acc16(v0);
        acc16(v1);
    }
    for (; j < nfull; ++j) {
        int e0 = src[s + 8 * j + g];
        uint4 v = x4[(size_t)e0 * 8 + c];
        acc16(v);
    }
    int b0 = s + 8 * nfull;
    int n = e - b0;  // 0..7
    if (g < n) {
        int e0 = src[b0 + g];
        uint4 v = x4[(size_t)e0 * 8 + c];
        acc16(v);
    }
    // reduce over edge-slots g (lanes xor 8,16,32)
#pragma unroll
    for (int q = 0; q < 16; ++q) {
        a[q] += __shfl_xor(a[q], 8);
        a[q] += __shfl_xor(a[q], 16);
        a[q] += __shfl_xor(a[q], 32);
    }
    if (t < 8) {  // lane c==t owns features t*16..t*16+15
        float inv = 1.f / fmaxf((float)deg, 1.f);
        unsigned o[8];
#pragma unroll
        for (int p = 0; p < 8; ++p)
            o[p] = (unsigned)f2bf(a[2 * p] * inv) |
                   ((unsigned)f2bf(a[2 * p + 1] * inv) << 16);
        uint4* hrow = (uint4*)hn + (size_t)d * 16 + t * 2;  // row = 16 uint4
        hrow[0] = make_uint4(o[0], o[1], o[2], o[3]);
        hrow[1] = make_uint4(o[4], o[5], o[6], o[7]);
    }
}

// ---- layer-2 mean agg: one wave/dst; 4 edges per dwordx4 wave-load ----
// h8 row = 256 B = 16 uint4. lane t: edge-slot g=t>>4, chunk c=t&15.
__global__ __launch_bounds__(256) void agg2b(const unsigned char* __restrict__ h8,
                                             const int* __restrict__ src,
                                             const int* __restrict__ rp,
                                             ushort* __restrict__ hn) {
    int t = threadIdx.x & 63;
    int d = blockIdx.x * 4 + (threadIdx.x >> 6);
    int s = rp[d], e = rp[d + 1];
    int deg = e - s;
    const uint4* h4 = (const uint4*)h8;  // row stride 16 uint4
    int g = t >> 4, c = t & 15;
    float a[16] = {};
    auto acc16 = [&](uint4 v) {
        f32x2 f;
        f = __builtin_amdgcn_cvt_pk_f32_fp8((int)v.x, false); a[0]  += f[0]; a[1]  += f[1];
        f = __builtin_amdgcn_cvt_pk_f32_fp8((int)v.x, true);  a[2]  += f[0]; a[3]  += f[1];
        f = __builtin_amdgcn_cvt_pk_f32_fp8((int)v.y, false); a[4]  += f[0]; a[5]  += f[1];
        f = __builtin_amdgcn_cvt_pk_f32_fp8((int)v.y, true);  a[6]  += f[0]; a[7]  += f[1];
        f = __builtin_amdgcn_cvt_pk_f32_fp8((int)v.z, false); a[8]  += f[0]; a[9]  += f[1];
        f = __builtin_amdgcn_cvt_pk_f32_fp8((int)v.z, true);  a[10] += f[0]; a[11] += f[1];
        f = __builtin_amdgcn_cvt_pk_f32_fp8((int)v.w, false); a[12] += f[0]; a[13] += f[1];
        f = __builtin_amdgcn_cvt_pk_f32_fp8((int)v.w, true);  a[14] += f[0]; a[15] += f[1];
    };
    int nfull = deg >> 2;
    int j = 0;
    for (; j + 2 <= nfull; j += 2) {
        int e0 = src[s + 4 * j + g];
        int e1 = src[s + 4 * j + 4 + g];
        uint4 v0 = h4[(size_t)e0 * 16 + c];
        uint4 v1 = h4[(size_t)e1 * 16 + c];
        acc16(v0);
        acc16(v1);
    }
    for (; j < nfull; ++j) {
        int e0 = src[s + 4 * j + g];
        uint4 v = h4[(size_t)e0 * 16 + c];
        acc16(v);
    }
    int b0 = s + 4 * nfull;
    int n = e - b0;  // 0..3
    if (g < n) {
        int e0 = src[b0 + g];
        uint4 v = h4[(size_t)e0 * 16 + c];
        acc16(v);
    }
    // reduce over edge-slots g (lanes xor 16,32)
#pragma unroll
    for (int q = 0; q < 16; ++q) {
        a[q] += __shfl_xor(a[q], 16);
        a[q] += __shfl_xor(a[q], 32);
    }
    if (t < 16) {  // lane c==t owns features t*16..t*16+15
        float inv = 1.f / fmaxf((float)deg, 1.f);
        unsigned o[8];
#pragma unroll
        for (int p = 0; p < 8; ++p)
            o[p] = (unsigned)f2bf(a[2 * p] * inv) |
                   ((unsigned)f2bf(a[2 * p + 1] * inv) << 16);
        uint4* hrow = (uint4*)hn + (size_t)d * 32 + t * 2;  // row = 32 uint4
        hrow[0] = make_uint4(o[0], o[1], o[2], o[3]);
        hrow[1] = make_uint4(o[4], o[5], o[6], o[7]);
    }
}

// ---- layer 1 GEMM (MFMA; self-A from fp32 x, neigh-A from bf16 hn1) ----
__global__ __launch_bounds__(256) void gemm1_mfma(
    const float* __restrict__ x, const ushort* __restrict__ hn1,
    const ushort* __restrict__ BpS, const ushort* __restrict__ BpN,
    const float* __restrict__ b1, ushort* __restrict__ hb,
    unsigned char* __restrict__ h8) {
    __shared__ ushort bsm[16 * 64 * 8];  // 16 KB stage
    int tid = threadIdx.x;
    int wave = tid >> 6, lane = tid & 63;
    int m0 = (blockIdx.x * 4 + wave) * 16;
    int mrow = m0 + (lane & 15);
    bool active = (m0 < N_DST1);
    if (mrow >= N_DST1) mrow = 0;
    int koff = (lane >> 4) * 8;

    f32x4 acc[16];
#pragma unroll
    for (int nb = 0; nb < 16; ++nb) acc[nb] = (f32x4){0.f, 0.f, 0.f, 0.f};

    for (int ph = 0; ph < 2; ++ph) {
        const uint4* Pg = (const uint4*)((ph == 0) ? BpS : BpN);
        const float*  Af = x   + (size_t)mrow * IN_F;
        const ushort* Ah = hn1 + (size_t)mrow * IN_F;
        for (int kb = 0; kb < 4; ++kb) {
            __syncthreads();
#pragma unroll
            for (int i = 0; i < 4; ++i) {
                int u = tid + 256 * i;
                int nb = u >> 6, l6 = u & 63;
                ((uint4*)bsm)[u] = Pg[(nb * 4 + kb) * 64 + l6];
            }
            __syncthreads();
            short8 a;
            if (ph == 0) {
                float4 a0 = *(const float4*)(Af + kb * 32 + koff);
                float4 a1 = *(const float4*)(Af + kb * 32 + koff + 4);
                a[0] = (short)f2bf(a0.x); a[1] = (short)f2bf(a0.y);
                a[2] = (short)f2bf(a0.z); a[3] = (short)f2bf(a0.w);
                a[4] = (short)f2bf(a1.x); a[5] = (short)f2bf(a1.y);
                a[6] = (short)f2bf(a1.z); a[7] = (short)f2bf(a1.w);
            } else {
                a = *(const short8*)(Ah + kb * 32 + koff);
            }
#pragma unroll
            for (int nb = 0; nb < 16; ++nb) {
                short8 b = *(const short8*)&bsm[(nb * 64 + lane) * 8];
                acc[nb] = __builtin_amdgcn_mfma_f32_16x16x32_bf16(a, b, acc[nb], 0, 0, 0);
            }
        }
    }
    if (!active) return;
    int crow0 = m0 + (lane >> 4) * 4;
    int ccol  = lane & 15;
#pragma unroll
    for (int nb = 0; nb < 16; ++nb) {
        float bias = b1[nb * 16 + ccol];
#pragma unroll
        for (int r = 0; r < 4; ++r) {
            int row = crow0 + r;
            if (row < N_DST1) {
                float v = fmaxf(acc[nb][r] + bias, 0.f);
                size_t col = (size_t)nb * 16 + ccol;
                hb[(size_t)row * H_F + col] = f2bf(v);
                int p = __builtin_amdgcn_cvt_pk_fp8_f32(v, v, 0, false);
                h8[(size_t)row * H_F + col] = (unsigned char)(p & 0xff);
            }
        }
    }
}

// ---- layer 2 GEMM (MFMA, K=512 over [hb|hn2], N padded to 48) ----
__global__ __launch_bounds__(256) void gemm2_mfma(
    const ushort* __restrict__ hb, const ushort* __restrict__ hn2,
    const ushort* __restrict__ P2, const float* __restrict__ b2,
    float* __restrict__ out) {
    int tid = threadIdx.x;
    int wave = tid >> 6, lane = tid & 63;
    int m0 = (blockIdx.x * 4 + wave) * 16;
    if (m0 >= N_DST2) return;
    int mrow = m0 + (lane & 15);
    int koff = (lane >> 4) * 8;

    f32x4 acc[3];
#pragma unroll
    for (int nb = 0; nb < 3; ++nb) acc[nb] = (f32x4){0.f, 0.f, 0.f, 0.f};

#pragma unroll
    for (int kb = 0; kb < 16; ++kb) {
        const ushort* A = (kb < 8)
            ? (hb  + (size_t)mrow * H_F + kb * 32 + koff)
            : (hn2 + (size_t)mrow * H_F + (kb - 8) * 32 + koff);
        short8 a = *(const short8*)A;
#pragma unroll
        for (int nb = 0; nb < 3; ++nb) {
            short8 b = *(const short8*)(P2 + ((size_t)(kb * 3 + nb) * 64 + lane) * 8);
            acc[nb] = __builtin_amdgcn_mfma_f32_16x16x32_bf16(a, b, acc[nb], 0, 0, 0);
        }
    }
    int crow0 = m0 + (lane >> 4) * 4;
    int ccol  = lane & 15;
#pragma unroll
    for (int nb = 0; nb < 3; ++nb) {
        int col = nb * 16 + ccol;
        if (col < N_CLS) {
            float bias = b2[col];
#pragma unroll
            for (int r = 0; r < 4; ++r)
                out[(size_t)(crow0 + r) * N_CLS + col] = acc[nb][r] + bias;
        }
    }
}

extern "C" void kernel_launch(void* const* d_in, const int* in_sizes, int n_in,
                              void* d_out, int out_size, void* d_ws, size_t ws_size,
                              hipStream_t stream) {
    const float* x   = (const float*)d_in[0];
    const float* Ws1 = (const float*)d_in[1];
    const float* Wn1 = (const float*)d_in[2];
    const float* b1  = (const float*)d_in[3];
    const float* Ws2 = (const float*)d_in[4];
    const float* Wn2 = (const float*)d_in[5];
    const float* b2  = (const float*)d_in[6];
    const int* src1  = (const int*)d_in[7];
    const int* dst1  = (const int*)d_in[8];
    const int* src2  = (const int*)d_in[9];
    const int* dst2  = (const int*)d_in[10];
    float* out = (float*)d_out;

    char* ws = (char*)d_ws;
    int*           rp1 = (int*)(ws + RP1_OFF);
    int*           rp2 = (int*)(ws + RP2_OFF);
    ushort*        bps = (ushort*)(ws + BPS_OFF);
    ushort*        bpn = (ushort*)(ws + BPN_OFF);
    ushort*        bp2 = (ushort*)(ws + BP2_OFF);
    unsigned char* x8  = (unsigned char*)(ws + X8_OFF);
    ushort*        hn1 = (ushort*)(ws + HN1_OFF);
    ushort*        hb  = (ushort*)(ws + HB_OFF);
    unsigned char* h8  = (unsigned char*)(ws + H8_OFF);
    ushort*        hn2 = (ushort*)(ws + HN2_OFF);

    setup_all<<<CAST_BLKS + PACK_BLKS + RP_BLKS, 256, 0, stream>>>(
        x, x8, Ws1, Wn1, Ws2, Wn2, bps, bpn, bp2, dst1, dst2, rp1, rp2);
    agg1b<<<N_DST1 / 4, 256, 0, stream>>>(x8, src1, rp1, hn1);
    gemm1_mfma<<<(N_DST1 / 16 + 3) / 4, 256, 0, stream>>>(x, hn1, bps, bpn, b1, hb, h8);
    agg2b<<<N_DST2 / 4, 256, 0, stream>>>(h8, src2, rp2, hn2);
    gemm2_mfma<<<(N_DST2 / 16 + 3) / 4, 256, 0, stream>>>(hb, hn2, bp2, b2, out);
}

// Round 9
// 299.179 us; speedup vs baseline: 1.6463x; 1.0167x over previous
//
#include <hip/hip_runtime.h>

constexpr int N_DST1 = 50000;
constexpr int N_DST2 = 10000;
constexpr int E1     = 2000000;
constexpr int E2     = 400000;
constexpr int IN_F   = 128;
constexpr int H_F    = 256;
constexpr int N_CLS  = 47;

// Workspace layout (bytes)
constexpr size_t RP1_OFF = 0;          // 50001 int
constexpr size_t RP2_OFF = 204800;     // 10001 int
constexpr size_t BPS_OFF = 245760;     // Ws1 packed bf16 frags: 64 KB
constexpr size_t BPN_OFF = 311296;     // Wn1 packed: 64 KB
constexpr size_t BP2_OFF = 376832;     // [Ws2;Wn2] packed: 48 KB
constexpr size_t X8_OFF  = 430080;     // x fp8: 200000*128 = 25.6 MB
constexpr size_t HN1_OFF = 26030080;   // hn1 bf16: 12.8 MB
constexpr size_t HB_OFF  = 38830080;   // h bf16 (rows < N_DST2 used): 25.6 MB region
constexpr size_t H8_OFF  = 64430080;   // h fp8: 12.8 MB
constexpr size_t HN2_OFF = 77230080;   // hn2 bf16: 5.12 MB
// total ~82.4 MB

using f32x4  = __attribute__((ext_vector_type(4))) float;
using f32x2  = __attribute__((ext_vector_type(2))) float;
using short8 = __attribute__((ext_vector_type(8))) short;

__device__ __forceinline__ ushort f2bf(float f) {
    union { float f; unsigned u; } v; v.f = f;
    unsigned u = v.u;
    return (ushort)((u + 0x7fffu + ((u >> 16) & 1u)) >> 16);
}

// ---- fused setup: cast x->fp8 | pack weights | rowptrs ----
constexpr int CAST_BLKS = 200000 * IN_F / 8 / 256;  // 12500
constexpr int PACK_BLKS = 44;
constexpr int RP_BLKS   = (N_DST1 + N_DST2 + 2 + 255) / 256;  // 236

__global__ __launch_bounds__(256) void setup_all(
    const float* __restrict__ x, unsigned char* __restrict__ x8,
    const float* __restrict__ Ws1, const float* __restrict__ Wn1,
    const float* __restrict__ Ws2, const float* __restrict__ Wn2,
    ushort* __restrict__ bps, ushort* __restrict__ bpn, ushort* __restrict__ bp2,
    const int* __restrict__ dst1, const int* __restrict__ dst2,
    int* __restrict__ rp1, int* __restrict__ rp2) {
    int b = blockIdx.x;
    if (b < CAST_BLKS) {
        int i = b * 256 + threadIdx.x;  // groups of 8 floats
        float4 v0 = ((const float4*)x)[2 * i];
        float4 v1 = ((const float4*)x)[2 * i + 1];
        int p0 = __builtin_amdgcn_cvt_pk_fp8_f32(v0.x, v0.y, 0, false);
        p0     = __builtin_amdgcn_cvt_pk_fp8_f32(v0.z, v0.w, p0, true);
        int p1 = __builtin_amdgcn_cvt_pk_fp8_f32(v1.x, v1.y, 0, false);
        p1     = __builtin_amdgcn_cvt_pk_fp8_f32(v1.z, v1.w, p1, true);
        uint2 o; o.x = (unsigned)p0; o.y = (unsigned)p1;
        ((uint2*)x8)[i] = o;
    } else if (b < CAST_BLKS + PACK_BLKS) {
        int pb = b - CAST_BLKS;
        if (pb < 32) {
            const float* W = (pb < 16) ? Ws1 : Wn1;
            ushort* P      = (pb < 16) ? bps : bpn;
            int idx = (pb & 15) * 256 + threadIdx.x;  // 0..4095
            int lane = idx & 63, kb = (idx >> 6) & 3, nb = idx >> 8;
            int n  = nb * 16 + (lane & 15);
            int k0 = kb * 32 + ((lane >> 4) * 8);
            ushort tmp[8];
#pragma unroll
            for (int j = 0; j < 8; ++j) tmp[j] = f2bf(W[(k0 + j) * H_F + n]);
            ((uint4*)P)[idx] = *(uint4*)tmp;
        } else {
            int idx = (pb - 32) * 256 + threadIdx.x;  // 0..3071
            if (idx < 3072) {
                int lane = idx & 63, rem = idx >> 6;
                int nb = rem % 3, kb = rem / 3;
                int col = nb * 16 + (lane & 15);
                int k0  = (kb & 7) * 32 + ((lane >> 4) * 8);
                const float* W = (kb < 8) ? Ws2 : Wn2;
                ushort tmp[8];
#pragma unroll
                for (int j = 0; j < 8; ++j)
                    tmp[j] = (col < N_CLS) ? f2bf(W[(k0 + j) * N_CLS + col]) : (ushort)0;
                ((uint4*)bp2)[(kb * 3 + nb) * 64 + lane] = *(uint4*)tmp;
            }
        }
    } else {
        int idx = (b - CAST_BLKS - PACK_BLKS) * 256 + threadIdx.x;
        const int* dst; int* rp; int E; int target;
        if (idx <= N_DST1) { dst = dst1; rp = rp1; E = E1; target = idx; }
        else if (idx <= N_DST1 + 1 + N_DST2) {
            dst = dst2; rp = rp2; E = E2; target = idx - (N_DST1 + 1);
        } else return;
        int lo = 0, hi = E;
        while (lo < hi) {
            int mid = (lo + hi) >> 1;
            if (dst[mid] < target) lo = mid + 1; else hi = mid;
        }
        rp[target] = lo;
    }
}

// ---- layer-1 mean agg: one wave/dst; 8 edges per dwordx4 wave-load ----
// x8 row = 128 B = 8 uint4. lane t: edge-slot g=t>>3, chunk c=t&7 (16 B).
__global__ __launch_bounds__(256) void agg1b(const unsigned char* __restrict__ x8,
                                             const int* __restrict__ src,
                                             const int* __restrict__ rp,
                                             ushort* __restrict__ hn) {
    int t = threadIdx.x & 63;
    int d = blockIdx.x * 4 + (threadIdx.x >> 6);
    int s = rp[d], e = rp[d + 1];
    int deg = e - s;
    const uint4* x4 = (const uint4*)x8;  // row stride 8 uint4
    int g = t >> 3, c = t & 7;
    float a[16] = {};
    auto acc16 = [&](uint4 v) {
        f32x2 f;
        f = __builtin_amdgcn_cvt_pk_f32_fp8((int)v.x, false); a[0]  += f[0]; a[1]  += f[1];
        f = __builtin_amdgcn_cvt_pk_f32_fp8((int)v.x, true);  a[2]  += f[0]; a[3]  += f[1];
        f = __builtin_amdgcn_cvt_pk_f32_fp8((int)v.y, false); a[4]  += f[0]; a[5]  += f[1];
        f = __builtin_amdgcn_cvt_pk_f32_fp8((int)v.y, true);  a[6]  += f[0]; a[7]  += f[1];
        f = __builtin_amdgcn_cvt_pk_f32_fp8((int)v.z, false); a[8]  += f[0]; a[9]  += f[1];
        f = __builtin_amdgcn_cvt_pk_f32_fp8((int)v.z, true);  a[10] += f[0]; a[11] += f[1];
        f = __builtin_amdgcn_cvt_pk_f32_fp8((int)v.w, false); a[12] += f[0]; a[13] += f[1];
        f = __builtin_amdgcn_cvt_pk_f32_fp8((int)v.w, true);  a[14] += f[0]; a[15] += f[1];
    };
    int nfull = deg >> 3;
    int j = 0;
    for (; j + 2 <= nfull; j += 2) {
        int e0 = src[s + 8 * j + g];
        int e1 = src[s + 8 * j + 8 + g];
        uint4 v0 = x4[(size_t)e0 * 8 + c];
        uint4 v1 = x4[(size_t)e1 * 8 + c];
        acc16(v0);
        acc16(v1);
    }
    for (; j < nfull; ++j) {
        int e0 = src[s + 8 * j + g];
        uint4 v = x4[(size_t)e0 * 8 + c];
        acc16(v);
    }
    int b0 = s + 8 * nfull;
    int n = e - b0;  // 0..7
    if (g < n) {
        int e0 = src[b0 + g];
        uint4 v = x4[(size_t)e0 * 8 + c];
        acc16(v);
    }
    // reduce over edge-slots g (lanes xor 8,16,32)
#pragma unroll
    for (int q = 0; q < 16; ++q) {
        a[q] += __shfl_xor(a[q], 8);
        a[q] += __shfl_xor(a[q], 16);
        a[q] += __shfl_xor(a[q], 32);
    }
    if (t < 8) {  // lane c==t owns features t*16..t*16+15
        float inv = 1.f / fmaxf((float)deg, 1.f);
        unsigned o[8];
#pragma unroll
        for (int p = 0; p < 8; ++p)
            o[p] = (unsigned)f2bf(a[2 * p] * inv) |
                   ((unsigned)f2bf(a[2 * p + 1] * inv) << 16);
        uint4* hrow = (uint4*)hn + (size_t)d * 16 + t * 2;  // row = 16 uint4
        hrow[0] = make_uint4(o[0], o[1], o[2], o[3]);
        hrow[1] = make_uint4(o[4], o[5], o[6], o[7]);
    }
}

// ---- layer-2 mean agg: one wave/dst; 4 edges per dwordx4 wave-load ----
// h8 row = 256 B = 16 uint4. lane t: edge-slot g=t>>4, chunk c=t&15.
__global__ __launch_bounds__(256) void agg2b(const unsigned char* __restrict__ h8,
                                             const int* __restrict__ src,
                                             const int* __restrict__ rp,
                                             ushort* __restrict__ hn) {
    int t = threadIdx.x & 63;
    int d = blockIdx.x * 4 + (threadIdx.x >> 6);
    int s = rp[d], e = rp[d + 1];
    int deg = e - s;
    const uint4* h4 = (const uint4*)h8;  // row stride 16 uint4
    int g = t >> 4, c = t & 15;
    float a[16] = {};
    auto acc16 = [&](uint4 v) {
        f32x2 f;
        f = __builtin_amdgcn_cvt_pk_f32_fp8((int)v.x, false); a[0]  += f[0]; a[1]  += f[1];
        f = __builtin_amdgcn_cvt_pk_f32_fp8((int)v.x, true);  a[2]  += f[0]; a[3]  += f[1];
        f = __builtin_amdgcn_cvt_pk_f32_fp8((int)v.y, false); a[4]  += f[0]; a[5]  += f[1];
        f = __builtin_amdgcn_cvt_pk_f32_fp8((int)v.y, true);  a[6]  += f[0]; a[7]  += f[1];
        f = __builtin_amdgcn_cvt_pk_f32_fp8((int)v.z, false); a[8]  += f[0]; a[9]  += f[1];
        f = __builtin_amdgcn_cvt_pk_f32_fp8((int)v.z, true);  a[10] += f[0]; a[11] += f[1];
        f = __builtin_amdgcn_cvt_pk_f32_fp8((int)v.w, false); a[12] += f[0]; a[13] += f[1];
        f = __builtin_amdgcn_cvt_pk_f32_fp8((int)v.w, true);  a[14] += f[0]; a[15] += f[1];
    };
    int nfull = deg >> 2;
    int j = 0;
    for (; j + 2 <= nfull; j += 2) {
        int e0 = src[s + 4 * j + g];
        int e1 = src[s + 4 * j + 4 + g];
        uint4 v0 = h4[(size_t)e0 * 16 + c];
        uint4 v1 = h4[(size_t)e1 * 16 + c];
        acc16(v0);
        acc16(v1);
    }
    for (; j < nfull; ++j) {
        int e0 = src[s + 4 * j + g];
        uint4 v = h4[(size_t)e0 * 16 + c];
        acc16(v);
    }
    int b0 = s + 4 * nfull;
    int n = e - b0;  // 0..3
    if (g < n) {
        int e0 = src[b0 + g];
        uint4 v = h4[(size_t)e0 * 16 + c];
        acc16(v);
    }
    // reduce over edge-slots g (lanes xor 16,32)
#pragma unroll
    for (int q = 0; q < 16; ++q) {
        a[q] += __shfl_xor(a[q], 16);
        a[q] += __shfl_xor(a[q], 32);
    }
    if (t < 16) {  // lane c==t owns features t*16..t*16+15
        float inv = 1.f / fmaxf((float)deg, 1.f);
        unsigned o[8];
#pragma unroll
        for (int p = 0; p < 8; ++p)
            o[p] = (unsigned)f2bf(a[2 * p] * inv) |
                   ((unsigned)f2bf(a[2 * p + 1] * inv) << 16);
        uint4* hrow = (uint4*)hn + (size_t)d * 32 + t * 2;  // row = 32 uint4
        hrow[0] = make_uint4(o[0], o[1], o[2], o[3]);
        hrow[1] = make_uint4(o[4], o[5], o[6], o[7]);
    }
}

// ---- layer 1 GEMM (MFMA; self-A from fp32 x, neigh-A from bf16 hn1) ----
__global__ __launch_bounds__(256) void gemm1_mfma(
    const float* __restrict__ x, const ushort* __restrict__ hn1,
    const ushort* __restrict__ BpS, const ushort* __restrict__ BpN,
    const float* __restrict__ b1, ushort* __restrict__ hb,
    unsigned char* __restrict__ h8) {
    __shared__ ushort bsm[16 * 64 * 8];  // 16 KB stage
    int tid = threadIdx.x;
    int wave = tid >> 6, lane = tid & 63;
    int m0 = (blockIdx.x * 4 + wave) * 16;
    int mrow = m0 + (lane & 15);
    bool active = (m0 < N_DST1);
    if (mrow >= N_DST1) mrow = 0;
    int koff = (lane >> 4) * 8;

    f32x4 acc[16];
#pragma unroll
    for (int nb = 0; nb < 16; ++nb) acc[nb] = (f32x4){0.f, 0.f, 0.f, 0.f};

    for (int ph = 0; ph < 2; ++ph) {
        const uint4* Pg = (const uint4*)((ph == 0) ? BpS : BpN);
        const float*  Af = x   + (size_t)mrow * IN_F;
        const ushort* Ah = hn1 + (size_t)mrow * IN_F;
        for (int kb = 0; kb < 4; ++kb) {
            __syncthreads();
#pragma unroll
            for (int i = 0; i < 4; ++i) {
                int u = tid + 256 * i;
                int nb = u >> 6, l6 = u & 63;
                ((uint4*)bsm)[u] = Pg[(nb * 4 + kb) * 64 + l6];
            }
            __syncthreads();
            short8 a;
            if (ph == 0) {
                float4 a0 = *(const float4*)(Af + kb * 32 + koff);
                float4 a1 = *(const float4*)(Af + kb * 32 + koff + 4);
                a[0] = (short)f2bf(a0.x); a[1] = (short)f2bf(a0.y);
                a[2] = (short)f2bf(a0.z); a[3] = (short)f2bf(a0.w);
                a[4] = (short)f2bf(a1.x); a[5] = (short)f2bf(a1.y);
                a[6] = (short)f2bf(a1.z); a[7] = (short)f2bf(a1.w);
            } else {
                a = *(const short8*)(Ah + kb * 32 + koff);
            }
#pragma unroll
            for (int nb = 0; nb < 16; ++nb) {
                short8 b = *(const short8*)&bsm[(nb * 64 + lane) * 8];
                acc[nb] = __builtin_amdgcn_mfma_f32_16x16x32_bf16(a, b, acc[nb], 0, 0, 0);
            }
        }
    }
    if (!active) return;
    int crow0 = m0 + (lane >> 4) * 4;
    int ccol  = lane & 15;
#pragma unroll
    for (int nb = 0; nb < 16; ++nb) {
        float bias = b1[nb * 16 + ccol];
#pragma unroll
        for (int r = 0; r < 4; ++r) {
            int row = crow0 + r;
            if (row < N_DST1) {
                float v = fmaxf(acc[nb][r] + bias, 0.f);
                size_t col = (size_t)nb * 16 + ccol;
                int p = __builtin_amdgcn_cvt_pk_fp8_f32(v, v, 0, false);
                h8[(size_t)row * H_F + col] = (unsigned char)(p & 0xff);
                // bf16 h only consumed by gemm2's self path (rows < N_DST2)
                if (row < N_DST2) hb[(size_t)row * H_F + col] = f2bf(v);
            }
        }
    }
}

// ---- layer 2 GEMM (MFMA, K=512 over [hb|hn2], N padded to 48) ----
__global__ __launch_bounds__(256) void gemm2_mfma(
    const ushort* __restrict__ hb, const ushort* __restrict__ hn2,
    const ushort* __restrict__ P2, const float* __restrict__ b2,
    float* __restrict__ out) {
    int tid = threadIdx.x;
    int wave = tid >> 6, lane = tid & 63;
    int m0 = (blockIdx.x * 4 + wave) * 16;
    if (m0 >= N_DST2) return;
    int mrow = m0 + (lane & 15);
    int koff = (lane >> 4) * 8;

    f32x4 acc[3];
#pragma unroll
    for (int nb = 0; nb < 3; ++nb) acc[nb] = (f32x4){0.f, 0.f, 0.f, 0.f};

#pragma unroll
    for (int kb = 0; kb < 16; ++kb) {
        const ushort* A = (kb < 8)
            ? (hb  + (size_t)mrow * H_F + kb * 32 + koff)
            : (hn2 + (size_t)mrow * H_F + (kb - 8) * 32 + koff);
        short8 a = *(const short8*)A;
#pragma unroll
        for (int nb = 0; nb < 3; ++nb) {
            short8 b = *(const short8*)(P2 + ((size_t)(kb * 3 + nb) * 64 + lane) * 8);
            acc[nb] = __builtin_amdgcn_mfma_f32_16x16x32_bf16(a, b, acc[nb], 0, 0, 0);
        }
    }
    int crow0 = m0 + (lane >> 4) * 4;
    int ccol  = lane & 15;
#pragma unroll
    for (int nb = 0; nb < 3; ++nb) {
        int col = nb * 16 + ccol;
        if (col < N_CLS) {
            float bias = b2[col];
#pragma unroll
            for (int r = 0; r < 4; ++r)
                out[(size_t)(crow0 + r) * N_CLS + col] = acc[nb][r] + bias;
        }
    }
}

extern "C" void kernel_launch(void* const* d_in, const int* in_sizes, int n_in,
                              void* d_out, int out_size, void* d_ws, size_t ws_size,
                              hipStream_t stream) {
    const float* x   = (const float*)d_in[0];
    const float* Ws1 = (const float*)d_in[1];
    const float* Wn1 = (const float*)d_in[2];
    const float* b1  = (const float*)d_in[3];
    const float* Ws2 = (const float*)d_in[4];
    const float* Wn2 = (const float*)d_in[5];
    const float* b2  = (const float*)d_in[6];
    const int* src1  = (const int*)d_in[7];
    const int* dst1  = (const int*)d_in[8];
    const int* src2  = (const int*)d_in[9];
    const int* dst2  = (const int*)d_in[10];
    float* out = (float*)d_out;

    char* ws = (char*)d_ws;
    int*           rp1 = (int*)(ws + RP1_OFF);
    int*           rp2 = (int*)(ws + RP2_OFF);
    ushort*        bps = (ushort*)(ws + BPS_OFF);
    ushort*        bpn = (ushort*)(ws + BPN_OFF);
    ushort*        bp2 = (ushort*)(ws + BP2_OFF);
    unsigned char* x8  = (unsigned char*)(ws + X8_OFF);
    ushort*        hn1 = (ushort*)(ws + HN1_OFF);
    ushort*        hb  = (ushort*)(ws + HB_OFF);
    unsigned char* h8  = (unsigned char*)(ws + H8_OFF);
    ushort*        hn2 = (ushort*)(ws + HN2_OFF);

    setup_all<<<CAST_BLKS + PACK_BLKS + RP_BLKS, 256, 0, stream>>>(
        x, x8, Ws1, Wn1, Ws2, Wn2, bps, bpn, bp2, dst1, dst2, rp1, rp2);
    agg1b<<<N_DST1 / 4, 256, 0, stream>>>(x8, src1, rp1, hn1);
    gemm1_mfma<<<(N_DST1 / 16 + 3) / 4, 256, 0, stream>>>(x, hn1, bps, bpn, b1, hb, h8);
    agg2b<<<N_DST2 / 4, 256, 0, stream>>>(h8, src2, rp2, hn2);
    gemm2_mfma<<<(N_DST2 / 16 + 3) / 4, 256, 0, stream>>>(hb, hn2, bp2, b2, out);
}

// Round 10
// 289.484 us; speedup vs baseline: 1.7014x; 1.0335x over previous
//
#include <hip/hip_runtime.h>

constexpr int N_DST1 = 50000;
constexpr int N_DST2 = 10000;
constexpr int E1     = 2000000;
constexpr int E2     = 400000;
constexpr int IN_F   = 128;
constexpr int H_F    = 256;
constexpr int N_CLS  = 47;

// Workspace layout (bytes)
constexpr size_t RP1_OFF = 0;          // 50001 int
constexpr size_t RP2_OFF = 204800;     // 10001 int
constexpr size_t BPS_OFF = 245760;     // Ws1 packed bf16 frags: 64 KB
constexpr size_t BPN_OFF = 311296;     // Wn1 packed: 64 KB
constexpr size_t BP2_OFF = 376832;     // [Ws2;Wn2] packed: 48 KB
constexpr size_t X8_OFF  = 430080;     // x fp8: 200000*128 = 25.6 MB
constexpr size_t HN1_OFF = 26030080;   // hn1 bf16: 12.8 MB
constexpr size_t HB_OFF  = 38830080;   // h bf16 (rows < N_DST2 used)
constexpr size_t H8_OFF  = 64430080;   // h fp8: 12.8 MB
constexpr size_t HN2_OFF = 77230080;   // hn2 bf16: 5.12 MB
// total ~82.4 MB

using f32x4  = __attribute__((ext_vector_type(4))) float;
using f32x2  = __attribute__((ext_vector_type(2))) float;
using short8 = __attribute__((ext_vector_type(8))) short;

__device__ __forceinline__ ushort f2bf(float f) {
    union { float f; unsigned u; } v; v.f = f;
    unsigned u = v.u;
    return (ushort)((u + 0x7fffu + ((u >> 16) & 1u)) >> 16);
}

// ---- fused setup: cast x->fp8 | pack weights | rowptrs ----
constexpr int CAST_BLKS = 200000 * IN_F / 8 / 256;  // 12500
constexpr int PACK_BLKS = 44;
constexpr int RP_BLKS   = (N_DST1 + N_DST2 + 2 + 255) / 256;  // 236

__global__ __launch_bounds__(256) void setup_all(
    const float* __restrict__ x, unsigned char* __restrict__ x8,
    const float* __restrict__ Ws1, const float* __restrict__ Wn1,
    const float* __restrict__ Ws2, const float* __restrict__ Wn2,
    ushort* __restrict__ bps, ushort* __restrict__ bpn, ushort* __restrict__ bp2,
    const int* __restrict__ dst1, const int* __restrict__ dst2,
    int* __restrict__ rp1, int* __restrict__ rp2) {
    int b = blockIdx.x;
    if (b < CAST_BLKS) {
        int i = b * 256 + threadIdx.x;  // groups of 8 floats
        float4 v0 = ((const float4*)x)[2 * i];
        float4 v1 = ((const float4*)x)[2 * i + 1];
        int p0 = __builtin_amdgcn_cvt_pk_fp8_f32(v0.x, v0.y, 0, false);
        p0     = __builtin_amdgcn_cvt_pk_fp8_f32(v0.z, v0.w, p0, true);
        int p1 = __builtin_amdgcn_cvt_pk_fp8_f32(v1.x, v1.y, 0, false);
        p1     = __builtin_amdgcn_cvt_pk_fp8_f32(v1.z, v1.w, p1, true);
        uint2 o; o.x = (unsigned)p0; o.y = (unsigned)p1;
        ((uint2*)x8)[i] = o;
    } else if (b < CAST_BLKS + PACK_BLKS) {
        int pb = b - CAST_BLKS;
        if (pb < 32) {
            const float* W = (pb < 16) ? Ws1 : Wn1;
            ushort* P      = (pb < 16) ? bps : bpn;
            int idx = (pb & 15) * 256 + threadIdx.x;  // 0..4095
            int lane = idx & 63, kb = (idx >> 6) & 3, nb = idx >> 8;
            int n  = nb * 16 + (lane & 15);
            int k0 = kb * 32 + ((lane >> 4) * 8);
            ushort tmp[8];
#pragma unroll
            for (int j = 0; j < 8; ++j) tmp[j] = f2bf(W[(k0 + j) * H_F + n]);
            ((uint4*)P)[idx] = *(uint4*)tmp;
        } else {
            int idx = (pb - 32) * 256 + threadIdx.x;  // 0..3071
            if (idx < 3072) {
                int lane = idx & 63, rem = idx >> 6;
                int nb = rem % 3, kb = rem / 3;
                int col = nb * 16 + (lane & 15);
                int k0  = (kb & 7) * 32 + ((lane >> 4) * 8);
                const float* W = (kb < 8) ? Ws2 : Wn2;
                ushort tmp[8];
#pragma unroll
                for (int j = 0; j < 8; ++j)
                    tmp[j] = (col < N_CLS) ? f2bf(W[(k0 + j) * N_CLS + col]) : (ushort)0;
                ((uint4*)bp2)[(kb * 3 + nb) * 64 + lane] = *(uint4*)tmp;
            }
        }
    } else {
        int idx = (b - CAST_BLKS - PACK_BLKS) * 256 + threadIdx.x;
        const int* dst; int* rp; int E; int target;
        if (idx <= N_DST1) { dst = dst1; rp = rp1; E = E1; target = idx; }
        else if (idx <= N_DST1 + 1 + N_DST2) {
            dst = dst2; rp = rp2; E = E2; target = idx - (N_DST1 + 1);
        } else return;
        int lo = 0, hi = E;
        while (lo < hi) {
            int mid = (lo + hi) >> 1;
            if (dst[mid] < target) lo = mid + 1; else hi = mid;
        }
        rp[target] = lo;
    }
}

// ---- layer-1 mean agg: one wave/dst; 8 edges per dwordx4 wave-load ----
// x8 row = 128 B = 8 uint4. lane t: edge-slot g=t>>3, chunk c=t&7 (16 B).
__global__ __launch_bounds__(256) void agg1b(const unsigned char* __restrict__ x8,
                                             const int* __restrict__ src,
                                             const int* __restrict__ rp,
                                             ushort* __restrict__ hn) {
    int t = threadIdx.x & 63;
    int d = blockIdx.x * 4 + (threadIdx.x >> 6);
    int s = rp[d], e = rp[d + 1];
    int deg = e - s;
    const uint4* x4 = (const uint4*)x8;  // row stride 8 uint4
    int g = t >> 3, c = t & 7;
    float a[16] = {};
    auto acc16 = [&](uint4 v) {
        f32x2 f;
        f = __builtin_amdgcn_cvt_pk_f32_fp8((int)v.x, false); a[0]  += f[0]; a[1]  += f[1];
        f = __builtin_amdgcn_cvt_pk_f32_fp8((int)v.x, true);  a[2]  += f[0]; a[3]  += f[1];
        f = __builtin_amdgcn_cvt_pk_f32_fp8((int)v.y, false); a[4]  += f[0]; a[5]  += f[1];
        f = __builtin_amdgcn_cvt_pk_f32_fp8((int)v.y, true);  a[6]  += f[0]; a[7]  += f[1];
        f = __builtin_amdgcn_cvt_pk_f32_fp8((int)v.z, false); a[8]  += f[0]; a[9]  += f[1];
        f = __builtin_amdgcn_cvt_pk_f32_fp8((int)v.z, true);  a[10] += f[0]; a[11] += f[1];
        f = __builtin_amdgcn_cvt_pk_f32_fp8((int)v.w, false); a[12] += f[0]; a[13] += f[1];
        f = __builtin_amdgcn_cvt_pk_f32_fp8((int)v.w, true);  a[14] += f[0]; a[15] += f[1];
    };
    int nfull = deg >> 3;
    int j = 0;
    for (; j + 2 <= nfull; j += 2) {
        int e0 = src[s + 8 * j + g];
        int e1 = src[s + 8 * j + 8 + g];
        uint4 v0 = x4[(size_t)e0 * 8 + c];
        uint4 v1 = x4[(size_t)e1 * 8 + c];
        acc16(v0);
        acc16(v1);
    }
    for (; j < nfull; ++j) {
        int e0 = src[s + 8 * j + g];
        uint4 v = x4[(size_t)e0 * 8 + c];
        acc16(v);
    }
    int b0 = s + 8 * nfull;
    int n = e - b0;  // 0..7
    if (g < n) {
        int e0 = src[b0 + g];
        uint4 v = x4[(size_t)e0 * 8 + c];
        acc16(v);
    }
    // reduce over edge-slots g (lanes xor 8,16,32)
#pragma unroll
    for (int q = 0; q < 16; ++q) {
        a[q] += __shfl_xor(a[q], 8);
        a[q] += __shfl_xor(a[q], 16);
        a[q] += __shfl_xor(a[q], 32);
    }
    if (t < 8) {  // lane c==t owns features t*16..t*16+15
        float inv = 1.f / fmaxf((float)deg, 1.f);
        unsigned o[8];
#pragma unroll
        for (int p = 0; p < 8; ++p)
            o[p] = (unsigned)f2bf(a[2 * p] * inv) |
                   ((unsigned)f2bf(a[2 * p + 1] * inv) << 16);
        uint4* hrow = (uint4*)hn + (size_t)d * 16 + t * 2;  // row = 16 uint4
        hrow[0] = make_uint4(o[0], o[1], o[2], o[3]);
        hrow[1] = make_uint4(o[4], o[5], o[6], o[7]);
    }
}

// ---- layer-2 mean agg: one wave/dst; 4 edges per dwordx4 wave-load ----
// h8 row = 256 B = 16 uint4. lane t: edge-slot g=t>>4, chunk c=t&15.
__global__ __launch_bounds__(256) void agg2b(const unsigned char* __restrict__ h8,
                                             const int* __restrict__ src,
                                             const int* __restrict__ rp,
                                             ushort* __restrict__ hn) {
    int t = threadIdx.x & 63;
    int d = blockIdx.x * 4 + (threadIdx.x >> 6);
    int s = rp[d], e = rp[d + 1];
    int deg = e - s;
    const uint4* h4 = (const uint4*)h8;  // row stride 16 uint4
    int g = t >> 4, c = t & 15;
    float a[16] = {};
    auto acc16 = [&](uint4 v) {
        f32x2 f;
        f = __builtin_amdgcn_cvt_pk_f32_fp8((int)v.x, false); a[0]  += f[0]; a[1]  += f[1];
        f = __builtin_amdgcn_cvt_pk_f32_fp8((int)v.x, true);  a[2]  += f[0]; a[3]  += f[1];
        f = __builtin_amdgcn_cvt_pk_f32_fp8((int)v.y, false); a[4]  += f[0]; a[5]  += f[1];
        f = __builtin_amdgcn_cvt_pk_f32_fp8((int)v.y, true);  a[6]  += f[0]; a[7]  += f[1];
        f = __builtin_amdgcn_cvt_pk_f32_fp8((int)v.z, false); a[8]  += f[0]; a[9]  += f[1];
        f = __builtin_amdgcn_cvt_pk_f32_fp8((int)v.z, true);  a[10] += f[0]; a[11] += f[1];
        f = __builtin_amdgcn_cvt_pk_f32_fp8((int)v.w, false); a[12] += f[0]; a[13] += f[1];
        f = __builtin_amdgcn_cvt_pk_f32_fp8((int)v.w, true);  a[14] += f[0]; a[15] += f[1];
    };
    int nfull = deg >> 2;
    int j = 0;
    for (; j + 2 <= nfull; j += 2) {
        int e0 = src[s + 4 * j + g];
        int e1 = src[s + 4 * j + 4 + g];
        uint4 v0 = h4[(size_t)e0 * 16 + c];
        uint4 v1 = h4[(size_t)e1 * 16 + c];
        acc16(v0);
        acc16(v1);
    }
    for (; j < nfull; ++j) {
        int e0 = src[s + 4 * j + g];
        uint4 v = h4[(size_t)e0 * 16 + c];
        acc16(v);
    }
    int b0 = s + 4 * nfull;
    int n = e - b0;  // 0..3
    if (g < n) {
        int e0 = src[b0 + g];
        uint4 v = h4[(size_t)e0 * 16 + c];
        acc16(v);
    }
    // reduce over edge-slots g (lanes xor 16,32)
#pragma unroll
    for (int q = 0; q < 16; ++q) {
        a[q] += __shfl_xor(a[q], 16);
        a[q] += __shfl_xor(a[q], 32);
    }
    if (t < 16) {  // lane c==t owns features t*16..t*16+15
        float inv = 1.f / fmaxf((float)deg, 1.f);
        unsigned o[8];
#pragma unroll
        for (int p = 0; p < 8; ++p)
            o[p] = (unsigned)f2bf(a[2 * p] * inv) |
                   ((unsigned)f2bf(a[2 * p + 1] * inv) << 16);
        uint4* hrow = (uint4*)hn + (size_t)d * 32 + t * 2;  // row = 32 uint4
        hrow[0] = make_uint4(o[0], o[1], o[2], o[3]);
        hrow[1] = make_uint4(o[4], o[5], o[6], o[7]);
    }
}

// ---- layer 1 GEMM: barrier-free, one wave = 16 rows x 64 cols; B from L2 ----
// 3125 blocks x 4 waves; wave w covers cols [w*64, w*64+64).
__global__ __launch_bounds__(256) void gemm1_mfma(
    const float* __restrict__ x, const ushort* __restrict__ hn1,
    const ushort* __restrict__ BpS, const ushort* __restrict__ BpN,
    const float* __restrict__ b1, ushort* __restrict__ hb,
    unsigned char* __restrict__ h8) {
    int tid = threadIdx.x;
    int wave = tid >> 6, lane = tid & 63;
    int m0 = blockIdx.x * 16;            // 3125 * 16 = 50000 exactly
    int nb0 = wave * 4;                  // 4 nb blocks of 16 cols each
    int mloc = lane & 15;
    int mrow = m0 + mloc;
    int koff = (lane >> 4) * 8;

    // hoisted A fragments: ph0 = x (fp32->bf16), ph1 = hn1 (bf16)
    const float*  Af = x   + (size_t)mrow * IN_F;
    const ushort* Ah = hn1 + (size_t)mrow * IN_F;
    short8 a0[4], a1[4];
#pragma unroll
    for (int kb = 0; kb < 4; ++kb) {
        float4 q0 = *(const float4*)(Af + kb * 32 + koff);
        float4 q1 = *(const float4*)(Af + kb * 32 + koff + 4);
        a0[kb][0] = (short)f2bf(q0.x); a0[kb][1] = (short)f2bf(q0.y);
        a0[kb][2] = (short)f2bf(q0.z); a0[kb][3] = (short)f2bf(q0.w);
        a0[kb][4] = (short)f2bf(q1.x); a0[kb][5] = (short)f2bf(q1.y);
        a0[kb][6] = (short)f2bf(q1.z); a0[kb][7] = (short)f2bf(q1.w);
        a1[kb] = *(const short8*)(Ah + kb * 32 + koff);
    }

    f32x4 acc[4];
#pragma unroll
    for (int nb = 0; nb < 4; ++nb) acc[nb] = (f32x4){0.f, 0.f, 0.f, 0.f};

#pragma unroll
    for (int kb = 0; kb < 4; ++kb)
#pragma unroll
        for (int nb = 0; nb < 4; ++nb) {
            short8 b = *(const short8*)(BpS + ((size_t)((nb0 + nb) * 4 + kb) * 64 + lane) * 8);
            acc[nb] = __builtin_amdgcn_mfma_f32_16x16x32_bf16(a0[kb], b, acc[nb], 0, 0, 0);
        }
#pragma unroll
    for (int kb = 0; kb < 4; ++kb)
#pragma unroll
        for (int nb = 0; nb < 4; ++nb) {
            short8 b = *(const short8*)(BpN + ((size_t)((nb0 + nb) * 4 + kb) * 64 + lane) * 8);
            acc[nb] = __builtin_amdgcn_mfma_f32_16x16x32_bf16(a1[kb], b, acc[nb], 0, 0, 0);
        }

    int crow0 = m0 + (lane >> 4) * 4;
    int ccol  = lane & 15;
#pragma unroll
    for (int nb = 0; nb < 4; ++nb) {
        size_t col = (size_t)(nb0 + nb) * 16 + ccol;
        float bias = b1[col];
#pragma unroll
        for (int r = 0; r < 4; ++r) {
            int row = crow0 + r;
            float v = fmaxf(acc[nb][r] + bias, 0.f);
            int p = __builtin_amdgcn_cvt_pk_fp8_f32(v, v, 0, false);
            h8[(size_t)row * H_F + col] = (unsigned char)(p & 0xff);
            if (row < N_DST2) hb[(size_t)row * H_F + col] = f2bf(v);
        }
    }
}

// ---- layer 2 GEMM (MFMA, K=512 over [hb|hn2], N padded to 48) ----
__global__ __launch_bounds__(256) void gemm2_mfma(
    const ushort* __restrict__ hb, const ushort* __restrict__ hn2,
    const ushort* __restrict__ P2, const float* __restrict__ b2,
    float* __restrict__ out) {
    int tid = threadIdx.x;
    int wave = tid >> 6, lane = tid & 63;
    int m0 = (blockIdx.x * 4 + wave) * 16;
    if (m0 >= N_DST2) return;
    int mrow = m0 + (lane & 15);
    int koff = (lane >> 4) * 8;

    f32x4 acc[3];
#pragma unroll
    for (int nb = 0; nb < 3; ++nb) acc[nb] = (f32x4){0.f, 0.f, 0.f, 0.f};

#pragma unroll
    for (int kb = 0; kb < 16; ++kb) {
        const ushort* A = (kb < 8)
            ? (hb  + (size_t)mrow * H_F + kb * 32 + koff)
            : (hn2 + (size_t)mrow * H_F + (kb - 8) * 32 + koff);
        short8 a = *(const short8*)A;
#pragma unroll
        for (int nb = 0; nb < 3; ++nb) {
            short8 b = *(const short8*)(P2 + ((size_t)(kb * 3 + nb) * 64 + lane) * 8);
            acc[nb] = __builtin_amdgcn_mfma_f32_16x16x32_bf16(a, b, acc[nb], 0, 0, 0);
        }
    }
    int crow0 = m0 + (lane >> 4) * 4;
    int ccol  = lane & 15;
#pragma unroll
    for (int nb = 0; nb < 3; ++nb) {
        int col = nb * 16 + ccol;
        if (col < N_CLS) {
            float bias = b2[col];
#pragma unroll
            for (int r = 0; r < 4; ++r)
                out[(size_t)(crow0 + r) * N_CLS + col] = acc[nb][r] + bias;
        }
    }
}

extern "C" void kernel_launch(void* const* d_in, const int* in_sizes, int n_in,
                              void* d_out, int out_size, void* d_ws, size_t ws_size,
                              hipStream_t stream) {
    const float* x   = (const float*)d_in[0];
    const float* Ws1 = (const float*)d_in[1];
    const float* Wn1 = (const float*)d_in[2];
    const float* b1  = (const float*)d_in[3];
    const float* Ws2 = (const float*)d_in[4];
    const float* Wn2 = (const float*)d_in[5];
    const float* b2  = (const float*)d_in[6];
    const int* src1  = (const int*)d_in[7];
    const int* dst1  = (const int*)d_in[8];
    const int* src2  = (const int*)d_in[9];
    const int* dst2  = (const int*)d_in[10];
    float* out = (float*)d_out;

    char* ws = (char*)d_ws;
    int*           rp1 = (int*)(ws + RP1_OFF);
    int*           rp2 = (int*)(ws + RP2_OFF);
    ushort*        bps = (ushort*)(ws + BPS_OFF);
    ushort*        bpn = (ushort*)(ws + BPN_OFF);
    ushort*        bp2 = (ushort*)(ws + BP2_OFF);
    unsigned char* x8  = (unsigned char*)(ws + X8_OFF);
    ushort*        hn1 = (ushort*)(ws + HN1_OFF);
    ushort*        hb  = (ushort*)(ws + HB_OFF);
    unsigned char* h8  = (unsigned char*)(ws + H8_OFF);
    ushort*        hn2 = (ushort*)(ws + HN2_OFF);

    setup_all<<<CAST_BLKS + PACK_BLKS + RP_BLKS, 256, 0, stream>>>(
        x, x8, Ws1, Wn1, Ws2, Wn2, bps, bpn, bp2, dst1, dst2, rp1, rp2);
    agg1b<<<N_DST1 / 4, 256, 0, stream>>>(x8, src1, rp1, hn1);
    gemm1_mfma<<<N_DST1 / 16, 256, 0, stream>>>(x, hn1, bps, bpn, b1, hb, h8);
    agg2b<<<N_DST2 / 4, 256, 0, stream>>>(h8, src2, rp2, hn2);
    gemm2_mfma<<<(N_DST2 / 16 + 3) / 4, 256, 0, stream>>>(hb, hn2, bp2, b2, out);
}